// Round 3
// baseline (235.488 us; speedup 1.0000x reference)
//
#include <hip/hip_runtime.h>
#include <cstdint>

#define B_    16
#define D_    64
#define N_    2304
#define DIN_  66
#define DI_   128
#define NT_   36                      // 64-row k tiles per batch
#define S2_   0.12751875732488788f    // (1/sqrt(128)) * log2(e)
#define NB_   ((size_t)B_ * N_ * DI_)
#define TSZ_  (64 * DI_)              // elements per swizzled tile

typedef __attribute__((ext_vector_type(8)))  short short8v;
typedef __attribute__((ext_vector_type(16))) float f32x16;

__device__ __forceinline__ unsigned short f2bf(float f) {
    unsigned u = __builtin_bit_cast(unsigned, f);
    u = (u + 0x7FFFu + ((u >> 16) & 1u)) >> 16;
    return (unsigned short)u;
}
__device__ __forceinline__ float bf2f(unsigned short h) {
    unsigned u = ((unsigned)h) << 16;
    return __builtin_bit_cast(float, u);
}
__device__ __forceinline__ unsigned cvtpk_bf16(float lo, float hi) {
    unsigned r;
    asm volatile("v_cvt_pk_bf16_f32 %0, %1, %2" : "=v"(r) : "v"(lo), "v"(hi));
    return r;
}
__device__ __forceinline__ void plswap(unsigned &a, unsigned &b) {
    asm volatile("v_permlane32_swap_b32 %0, %1" : "+v"(a), "+v"(b));
}

// async global->LDS: wave-uniform LDS base, per-lane global src (16B/lane)
__device__ __forceinline__ void stage_tile(const unsigned short* g,
                                           unsigned short* l, int w, int ln) {
    #pragma unroll
    for (int i = 0; i < 2; ++i) {
        const unsigned short* gp = g + i * 4096 + w * 512 + ln * 8;
        unsigned short* lp = l + i * 4096 + w * 512;
        __builtin_amdgcn_global_load_lds(
            (const __attribute__((address_space(1))) void*)gp,
            (__attribute__((address_space(3))) void*)lp, 16, 0, 0);
    }
}

// ---------------------------------------------------------------------------
// Kernel 1: QKV projection via MFMA (unchanged from r2 — verified).
// ---------------------------------------------------------------------------
__global__ __launch_bounds__(256) void qkv_kernel(
    const float* __restrict__ x,
    const float* __restrict__ Wq, const float* __restrict__ Wk,
    const float* __restrict__ Wv,
    unsigned short* __restrict__ Qb, unsigned short* __restrict__ Kb,
    unsigned short* __restrict__ Vn)
{
    __shared__ unsigned short Es[128 * 88];
    __shared__ unsigned short Ws[384 * 88];
    const int t = threadIdx.x;
    const int b = blockIdx.x / 18, nt = blockIdx.x - b * 18;
    const int n0 = nt * 128;

    {   // x -> Es transposed bf16 (cols 0..63)
        const int d = t & 63, q4 = t >> 6;
        const float* xp = x + ((size_t)b * D_ + d) * N_ + n0 + q4 * 32;
        float xv[32];
        #pragma unroll
        for (int i = 0; i < 8; ++i) *(float4*)(xv + 4 * i) = *(const float4*)(xp + 4 * i);
        #pragma unroll
        for (int i = 0; i < 32; ++i) Es[(q4 * 32 + i) * 88 + d] = f2bf(xv[i]);
    }
    if (t < 128) {
        int n = n0 + t;
        int ix = n / 48, iy = n - ix * 48;
        Es[t * 88 + 64] = f2bf(-1.0f + ((float)ix + 0.5f) * (2.0f / 48.0f));
        Es[t * 88 + 65] = f2bf(-1.0f + ((float)iy + 0.5f) * (2.0f / 48.0f));
        #pragma unroll
        for (int m = 0; m < 7; ++m) *(unsigned*)&Es[t * 88 + 66 + 2 * m] = 0;
    }
    for (int i = 0; i < 99; ++i) {
        int idx = i * 256 + t;
        int r = idx / 66, c = idx - r * 66;
        const float* src = (idx < 8448) ? (Wq + idx)
                         : (idx < 16896) ? (Wk + idx - 8448) : (Wv + idx - 16896);
        Ws[r * 88 + c] = f2bf(*src);
    }
    for (int u = t; u < 384 * 7; u += 256) {
        int r = u / 7, c = 66 + 2 * (u - r * 7);
        *(unsigned*)&Ws[r * 88 + c] = 0;
    }
    __syncthreads();

    const int l = t & 63, w = t >> 6;
    const int m32 = l & 31, H = l >> 5;
    const int colbase = w * 96;
    #pragma unroll
    for (int nf = 0; nf < 4; ++nf) {
        f32x16 acc[3];
        #pragma unroll
        for (int of = 0; of < 3; ++of)
            #pragma unroll
            for (int i = 0; i < 16; ++i) acc[of][i] = 0.0f;
        #pragma unroll
        for (int kc = 0; kc < 5; ++kc) {
            short8v a = *(const short8v*)&Es[(nf * 32 + m32) * 88 + kc * 16 + H * 8];
            #pragma unroll
            for (int of = 0; of < 3; ++of) {
                short8v bf = *(const short8v*)&Ws[(colbase + of * 32 + m32) * 88 + kc * 16 + H * 8];
                acc[of] = __builtin_amdgcn_mfma_f32_32x32x16_bf16(a, bf, acc[of], 0, 0, 0);
            }
        }
        #pragma unroll
        for (int of = 0; of < 3; ++of) {
            int col0 = colbase + of * 32;
            int mi = col0 >> 7, e0 = col0 & 127;
            unsigned short* dst = (mi == 0) ? Qb : (mi == 1) ? Kb : Vn;
            #pragma unroll
            for (int r = 0; r < 16; ++r) {
                int n = n0 + nf * 32 + (r & 3) + 8 * (r >> 2) + 4 * H;
                dst[((size_t)b * N_ + n) * DI_ + e0 + m32] = f2bf(acc[of][r]);
            }
        }
    }
}

// ---------------------------------------------------------------------------
// Kernel 2: Kb rows -> Ksw pre-swizzled tile images (linear DMA == swizzled LDS)
// tile image [64 rows][16 chunks of 16B]; position p holds source chunk p^(r&15)
// ---------------------------------------------------------------------------
__global__ __launch_bounds__(256) void repackK_kernel(
    const unsigned short* __restrict__ Kb, unsigned short* __restrict__ Ksw)
{
    const int blk = blockIdx.x;          // 16*36
    const int b = blk / NT_, kt = blk - b * NT_;
    const int t = threadIdx.x;
    const size_t src = ((size_t)b * N_ + kt * 64) * DI_;
    const size_t dst = ((size_t)b * NT_ + kt) * TSZ_;
    #pragma unroll
    for (int i = 0; i < 4; ++i) {
        int o = i * 256 + t;             // output chunk 0..1023
        int r = o >> 4, cp = o & 15;
        int c = cp ^ (r & 15);
        *(int4*)(Ksw + dst + (size_t)o * 8) = *(const int4*)(Kb + src + r * DI_ + c * 8);
    }
}

// ---------------------------------------------------------------------------
// Kernel 3: Zg[b][k] = sum_q exp2(S2 * dot(Q[q],K[k]))  (atomic-accumulated)
// S = Q.K^T orientation: A = qreg (2 frags, reuse 2x), B = K-frag from LDS.
// C-frag col = k  ->  sum over q is a pure in-lane reduction + LDS atomic.
// grid 144 (16b x 9 qtile(256)), 512 thr, waves (w_q 4 x w_k 2).
// ---------------------------------------------------------------------------
__global__ __launch_bounds__(512, 2) void zsum_kernel(
    const unsigned short* __restrict__ Qb, const unsigned short* __restrict__ Ksw,
    float* __restrict__ Zg)
{
    __shared__ unsigned short Ks[2][TSZ_];
    __shared__ float Zacc[N_];
    const int t = threadIdx.x;
    const int blk = blockIdx.x;
    const int b = 2 * (blk & 7) + ((blk >> 3) / 9);
    const int qt = (blk >> 3) % 9;
    const int q0 = qt * 256;
    const int l = t & 63, w = t >> 6;
    const int wk = w & 1, wq = w >> 1;
    const int m32 = l & 31, m15 = l & 15, H = l >> 5;

    for (int i = t; i < N_; i += 512) Zacc[i] = 0.0f;

    short8v qreg[2][8];   // A-frags [32q x 16e], lane row = m32
    {
        const unsigned short* qp = Qb + ((size_t)b * N_ + q0 + wq * 64 + m32) * DI_ + H * 8;
        #pragma unroll
        for (int qf = 0; qf < 2; ++qf)
            #pragma unroll
            for (int ec = 0; ec < 8; ++ec)
                qreg[qf][ec] = *(const short8v*)(qp + (size_t)qf * 32 * DI_ + ec * 16);
    }
    const unsigned short* kswb = Ksw + (size_t)b * NT_ * TSZ_;
    stage_tile(kswb, &Ks[0][0], w, l);
    asm volatile("s_waitcnt vmcnt(0)" ::: "memory");
    __syncthreads();

    for (int kt = 0; kt < NT_; ++kt) {
        if (kt + 1 < NT_) stage_tile(kswb + (size_t)(kt + 1) * TSZ_, &Ks[(kt + 1) & 1][0], w, l);
        const unsigned short* kb = &Ks[kt & 1][0];
        f32x16 sacc[2];
        #pragma unroll
        for (int qf = 0; qf < 2; ++qf)
            #pragma unroll
            for (int i = 0; i < 16; ++i) sacc[qf][i] = 0.0f;
        #pragma unroll
        for (int ec = 0; ec < 8; ++ec) {
            short8v bk = *(const short8v*)&kb[(wk * 32 + m32) * DI_ + ((((ec << 1) | H) ^ m15) * 8)];
            sacc[0] = __builtin_amdgcn_mfma_f32_32x32x16_bf16(qreg[0][ec], bk, sacc[0], 0, 0, 0);
            sacc[1] = __builtin_amdgcn_mfma_f32_32x32x16_bf16(qreg[1][ec], bk, sacc[1], 0, 0, 0);
        }
        float zl = 0.0f;
        #pragma unroll
        for (int qf = 0; qf < 2; ++qf)
            #pragma unroll
            for (int r = 0; r < 16; ++r)
                zl += exp2f(sacc[qf][r] * S2_);
        atomicAdd(&Zacc[kt * 64 + wk * 32 + m32], zl);
        asm volatile("s_waitcnt vmcnt(0)" ::: "memory");
        __syncthreads();
    }
    for (int i = t; i < N_; i += 512)
        atomicAdd(&Zg[(size_t)b * N_ + i], Zacc[i]);
}

// ---------------------------------------------------------------------------
// Kernel 4: Vn + Zg -> Vsw: pre-swizzled Vz^T tile images.
// image row r, pos p: source chunk c = p^(r&15); content = V[k0+ (c&7)*8+j][d]/Z,
// d = (c>>3)*64 + r.
// ---------------------------------------------------------------------------
__global__ __launch_bounds__(256) void repackV_kernel(
    const unsigned short* __restrict__ Vn, const float* __restrict__ Zg,
    unsigned short* __restrict__ Vsw)
{
    __shared__ unsigned short Vstg[64 * 132];
    __shared__ float zinv[64];
    const int blk = blockIdx.x;
    const int b = blk / NT_, kt = blk - b * NT_;
    const int t = threadIdx.x;
    const int k0 = kt * 64;
    {
        const int k = t >> 2, c = (t & 3) * 32;
        const unsigned short* src = Vn + ((size_t)b * N_ + k0 + k) * DI_ + c;
        #pragma unroll
        for (int i = 0; i < 4; ++i)
            *(int4*)&Vstg[k * 132 + c + i * 8] = *(const int4*)(src + i * 8);
    }
    if (t < 64) zinv[t] = 1.0f / Zg[(size_t)b * N_ + k0 + t];
    __syncthreads();
    const size_t dst = ((size_t)b * NT_ + kt) * TSZ_;
    #pragma unroll
    for (int i = 0; i < 4; ++i) {
        int o = i * 256 + t;
        int r = o >> 4, cp = o & 15;
        int c = cp ^ (r & 15);
        int d = (c >> 3) * 64 + r;
        int kc = c & 7;
        unsigned short outc[8];
        #pragma unroll
        for (int j = 0; j < 8; ++j)
            outc[j] = f2bf(bf2f(Vstg[(kc * 8 + j) * 132 + d]) * zinv[kc * 8 + j]);
        *(int4*)(Vsw + dst + (size_t)o * 8) = *(const int4*)outc;
    }
}

// ---------------------------------------------------------------------------
// Kernel 5: Out^T = Vz^T . P  with  P = exp2(S2*S) recomputed, S^T = K.Q^T.
// waves (w_k 2 x w_q 4): qreg 2 B-frags (reuse 2x), V A-frag reuse 2x,
// P in-register (cvt_pk + permlane32_swap).  Cross-w_k oacc reduce at end.
// grid 144 (16b x 9 qtile(256)), 512 thr.
// ---------------------------------------------------------------------------
__global__ __launch_bounds__(512, 2) void attn_kernel(
    const unsigned short* __restrict__ Qb, const unsigned short* __restrict__ Ksw,
    const unsigned short* __restrict__ Vsw, float* __restrict__ Out)
{
    __shared__ unsigned short Ks[2][TSZ_];
    __shared__ unsigned short Vs[2][TSZ_];
    const int t = threadIdx.x;
    const int blk = blockIdx.x;
    const int b = 2 * (blk & 7) + ((blk >> 3) / 9);
    const int qt = (blk >> 3) % 9;
    const int q0 = qt * 256;
    const int l = t & 63, w = t >> 6;
    const int wk = w & 1, wq = w >> 1;
    const int m32 = l & 31, m15 = l & 15, H = l >> 5;

    short8v qreg[2][8];   // B-frags [16e x 32q], lane col = m32
    {
        const unsigned short* qp = Qb + ((size_t)b * N_ + q0 + wq * 64 + m32) * DI_ + H * 8;
        #pragma unroll
        for (int qf = 0; qf < 2; ++qf)
            #pragma unroll
            for (int ec = 0; ec < 8; ++ec)
                qreg[qf][ec] = *(const short8v*)(qp + (size_t)qf * 32 * DI_ + ec * 16);
    }
    f32x16 oacc[4][2];
    #pragma unroll
    for (int df = 0; df < 4; ++df)
        #pragma unroll
        for (int qf = 0; qf < 2; ++qf)
            #pragma unroll
            for (int i = 0; i < 16; ++i) oacc[df][qf][i] = 0.0f;

    const unsigned short* kswb = Ksw + (size_t)b * NT_ * TSZ_;
    const unsigned short* vswb = Vsw + (size_t)b * NT_ * TSZ_;
    stage_tile(kswb, &Ks[0][0], w, l);
    stage_tile(vswb, &Vs[0][0], w, l);
    asm volatile("s_waitcnt vmcnt(0)" ::: "memory");
    __syncthreads();

    for (int kt = 0; kt < NT_; ++kt) {
        if (kt + 1 < NT_) {
            stage_tile(kswb + (size_t)(kt + 1) * TSZ_, &Ks[(kt + 1) & 1][0], w, l);
            stage_tile(vswb + (size_t)(kt + 1) * TSZ_, &Vs[(kt + 1) & 1][0], w, l);
        }
        const unsigned short* kb = &Ks[kt & 1][0];
        const unsigned short* vb = &Vs[kt & 1][0];

        // ---- S^T = K.Q^T : A = K-frag [32k x 16e] (lane row = m32) ----
        f32x16 sacc[2];
        #pragma unroll
        for (int qf = 0; qf < 2; ++qf)
            #pragma unroll
            for (int i = 0; i < 16; ++i) sacc[qf][i] = 0.0f;
        #pragma unroll
        for (int ec = 0; ec < 8; ++ec) {
            short8v ak = *(const short8v*)&kb[(wk * 32 + m32) * DI_ + ((((ec << 1) | H) ^ m15) * 8)];
            sacc[0] = __builtin_amdgcn_mfma_f32_32x32x16_bf16(ak, qreg[0][ec], sacc[0], 0, 0, 0);
            sacc[1] = __builtin_amdgcn_mfma_f32_32x32x16_bf16(ak, qreg[1][ec], sacc[1], 0, 0, 0);
        }
        // ---- P = exp2, pack to bf16 B-frags [16k x 32q] ----
        unsigned pB[2][2][4];
        #pragma unroll
        for (int qf = 0; qf < 2; ++qf) {
            float p[16];
            #pragma unroll
            for (int r = 0; r < 16; ++r) p[r] = exp2f(sacc[qf][r] * S2_);
            unsigned c0[4], c1[4];
            #pragma unroll
            for (int m = 0; m < 4; ++m) {
                c0[m] = cvtpk_bf16(p[4 * m],     p[4 * m + 1]);
                c1[m] = cvtpk_bf16(p[4 * m + 2], p[4 * m + 3]);
            }
            #pragma unroll
            for (int kq = 0; kq < 2; ++kq) {
                unsigned d0 = c0[2 * kq], d2 = c0[2 * kq + 1];
                plswap(d0, d2);
                unsigned d1 = c1[2 * kq], d3 = c1[2 * kq + 1];
                plswap(d1, d3);
                pB[qf][kq][0] = d0; pB[qf][kq][1] = d1;
                pB[qf][kq][2] = d2; pB[qf][kq][3] = d3;
            }
        }
        // ---- O^T += Vz^T . P : A = Vz-frag [32d x 16k] (reuse 2x) ----
        #pragma unroll
        for (int df = 0; df < 4; ++df) {
            const int rr = (df & 1) * 32 + m32;
            const int cbase = (df >> 1) * 8 + wk * 4;
            #pragma unroll
            for (int kq = 0; kq < 2; ++kq) {
                const int c = cbase + kq * 2 + H;
                short8v av = *(const short8v*)&vb[rr * DI_ + ((c ^ (rr & 15)) * 8)];
                #pragma unroll
                for (int qf = 0; qf < 2; ++qf) {
                    int4 t4;
                    t4.x = (int)pB[qf][kq][0]; t4.y = (int)pB[qf][kq][1];
                    t4.z = (int)pB[qf][kq][2]; t4.w = (int)pB[qf][kq][3];
                    short8v pb = __builtin_bit_cast(short8v, t4);
                    oacc[df][qf] = __builtin_amdgcn_mfma_f32_32x32x16_bf16(av, pb, oacc[df][qf], 0, 0, 0);
                }
            }
        }
        asm volatile("s_waitcnt vmcnt(0)" ::: "memory");
        __syncthreads();
    }

    // ---- cross-w_k reduction of oacc via LDS (reuse Ks area, 32 KB) ----
    float* red = (float*)&Ks[0][0];
    #pragma unroll
    for (int df = 0; df < 4; ++df) {
        if (wk == 1) {
            #pragma unroll
            for (int qf = 0; qf < 2; ++qf)
                #pragma unroll
                for (int r = 0; r < 16; ++r)
                    red[(wq * 2 + qf) * 1024 + r * 64 + l] = oacc[df][qf][r];
        }
        __syncthreads();
        if (wk == 0) {
            #pragma unroll
            for (int qf = 0; qf < 2; ++qf)
                #pragma unroll
                for (int r = 0; r < 16; ++r)
                    oacc[df][qf][r] += red[(wq * 2 + qf) * 1024 + r * 64 + l];
        }
        __syncthreads();
    }
    if (wk == 0) {
        float* outp = Out + ((size_t)b * N_ + q0 + wq * 64) * DI_;
        #pragma unroll
        for (int df = 0; df < 4; ++df)
            #pragma unroll
            for (int qf = 0; qf < 2; ++qf)
                #pragma unroll
                for (int r = 0; r < 16; ++r) {
                    int q = qf * 32 + m32;
                    int d = df * 32 + (r & 3) + 8 * (r >> 2) + 4 * H;
                    outp[(size_t)q * DI_ + d] = oacc[df][qf][r];
                }
    }
}

// ---------------------------------------------------------------------------
extern "C" void kernel_launch(void* const* d_in, const int* in_sizes, int n_in,
                              void* d_out, int out_size, void* d_ws, size_t ws_size,
                              hipStream_t stream)
{
    const float* x  = (const float*)d_in[0];
    const float* Wq = (const float*)d_in[1];
    const float* Wk = (const float*)d_in[2];
    const float* Wv = (const float*)d_in[3];

    unsigned short* Qb  = (unsigned short*)d_ws;    // [B][N][128] bf16 rows
    unsigned short* Kb  = Qb  + NB_;                // [B][N][128] bf16 rows
    unsigned short* Vn  = Kb  + NB_;                // [B][N][128] bf16 rows
    unsigned short* Ksw = Vn  + NB_;                // [B][36] swizzled tiles
    unsigned short* Vsw = Ksw + NB_;                // [B][36] swizzled Vz^T tiles
    float*          Zg  = (float*)(Vsw + NB_);      // [B][N] f32 col sums
    float* out = (float*)d_out;

    hipMemsetAsync(Zg, 0, (size_t)B_ * N_ * sizeof(float), stream);
    qkv_kernel    <<<288, 256, 0, stream>>>(x, Wq, Wk, Wv, Qb, Kb, Vn);
    repackK_kernel<<<576, 256, 0, stream>>>(Kb, Ksw);
    zsum_kernel   <<<144, 512, 0, stream>>>(Qb, Ksw, Zg);
    repackV_kernel<<<576, 256, 0, stream>>>(Vn, Zg, Vsw);
    attn_kernel   <<<144, 512, 0, stream>>>(Qb, Ksw, Vsw, out);
}

// Round 4
// 194.450 us; speedup vs baseline: 1.2110x; 1.2110x over previous
//
#include <hip/hip_runtime.h>
#include <cstdint>

#define B_    16
#define D_    64
#define N_    2304
#define DI_   128
#define S2_   0.12751875732488788f    // (1/sqrt(128)) * log2(e)
#define NB_   ((size_t)B_ * N_ * DI_)
#define KTSZ_ 4096                    // K tile: 32k x 128e shorts
#define VTSZ_ 4608                    // V tile: 128d x 36 shorts (pitch 72B)
#define NKT_  72                      // 32-row k tiles per batch

typedef __attribute__((ext_vector_type(4)))  short short4v;
typedef __attribute__((ext_vector_type(8)))  short short8v;
typedef __attribute__((ext_vector_type(16))) float f32x16;

__device__ __forceinline__ unsigned short f2bf(float f) {
    unsigned u = __builtin_bit_cast(unsigned, f);
    u = (u + 0x7FFFu + ((u >> 16) & 1u)) >> 16;
    return (unsigned short)u;
}
__device__ __forceinline__ float bf2f(unsigned short h) {
    unsigned u = ((unsigned)h) << 16;
    return __builtin_bit_cast(float, u);
}
__device__ __forceinline__ unsigned cvtpk_bf16(float lo, float hi) {
    unsigned r;
    asm volatile("v_cvt_pk_bf16_f32 %0, %1, %2" : "=v"(r) : "v"(lo), "v"(hi));
    return r;
}
__device__ __forceinline__ void plswap(unsigned &a, unsigned &b) {
    asm volatile("v_permlane32_swap_b32 %0, %1" : "+v"(a), "+v"(b));
}
union V8u { short8v v8; short4v v4[2]; };

// DMA helpers: wave-uniform LDS base + lane*16B
__device__ __forceinline__ void stage_k(const unsigned short* g,
                                        unsigned short* l, int w, int ln) {
    #pragma unroll
    for (int i = 0; i < 2; ++i)
        __builtin_amdgcn_global_load_lds(
            (const __attribute__((address_space(1))) void*)(g + i * 2048 + w * 512 + ln * 8),
            (__attribute__((address_space(3))) void*)(l + i * 2048 + w * 512), 16, 0, 0);
}
__device__ __forceinline__ void stage_v(const unsigned short* g,
                                        unsigned short* l, int w, int ln, int t) {
    #pragma unroll
    for (int i = 0; i < 2; ++i)
        __builtin_amdgcn_global_load_lds(
            (const __attribute__((address_space(1))) void*)(g + i * 2048 + w * 512 + ln * 8),
            (__attribute__((address_space(3))) void*)(l + i * 2048 + w * 512), 16, 0, 0);
    if (t < 64)
        __builtin_amdgcn_global_load_lds(
            (const __attribute__((address_space(1))) void*)(g + 4096 + ln * 8),
            (__attribute__((address_space(3))) void*)(l + 4096), 16, 0, 0);
}

// ---------------------------------------------------------------------------
// Kernel 0: W -> W3p [384][88] bf16 (rows: Wq,Wk,Wv; cols 66..87 zero)
// ---------------------------------------------------------------------------
__global__ __launch_bounds__(256) void wprep_kernel(
    const float* __restrict__ Wq, const float* __restrict__ Wk,
    const float* __restrict__ Wv, unsigned short* __restrict__ W3p)
{
    const int t = threadIdx.x;
    for (int r = t; r < 384; r += 256) {
        const float* src = (r < 128) ? (Wq + r * 66)
                         : (r < 256) ? (Wk + (r - 128) * 66) : (Wv + (r - 256) * 66);
        for (int c = 0; c < 66; ++c) W3p[r * 88 + c] = f2bf(src[c]);
        for (int c = 66; c < 88; ++c) W3p[r * 88 + c] = 0;
    }
}

// ---------------------------------------------------------------------------
// Kernel 1: QKV projection via MFMA; W read direct from global (L2-hot).
// grid 16b x 18nt(128), 256 thr.
// ---------------------------------------------------------------------------
__global__ __launch_bounds__(256) void qkv_kernel(
    const float* __restrict__ x, const unsigned short* __restrict__ W3p,
    unsigned short* __restrict__ Qb, unsigned short* __restrict__ Kb,
    unsigned short* __restrict__ Vn)
{
    __shared__ unsigned short Es[128 * 88];
    const int t = threadIdx.x;
    const int b = blockIdx.x / 18, nt = blockIdx.x - b * 18;
    const int n0 = nt * 128;

    {   // x -> Es transposed bf16 (cols 0..63)
        const int d = t & 63, q4 = t >> 6;
        const float* xp = x + ((size_t)b * D_ + d) * N_ + n0 + q4 * 32;
        float xv[32];
        #pragma unroll
        for (int i = 0; i < 8; ++i) *(float4*)(xv + 4 * i) = *(const float4*)(xp + 4 * i);
        #pragma unroll
        for (int i = 0; i < 32; ++i) Es[(q4 * 32 + i) * 88 + d] = f2bf(xv[i]);
    }
    if (t < 128) {  // coords + zero pad
        int n = n0 + t;
        int ix = n / 48, iy = n - ix * 48;
        Es[t * 88 + 64] = f2bf(-1.0f + ((float)ix + 0.5f) * (2.0f / 48.0f));
        Es[t * 88 + 65] = f2bf(-1.0f + ((float)iy + 0.5f) * (2.0f / 48.0f));
        #pragma unroll
        for (int m = 0; m < 11; ++m) *(unsigned*)&Es[t * 88 + 66 + 2 * m] = 0;
    }
    __syncthreads();

    const int l = t & 63, w = t >> 6;
    const int m32 = l & 31, H = l >> 5;
    const int colbase = w * 96;
    #pragma unroll
    for (int nf = 0; nf < 4; ++nf) {
        f32x16 acc[3];
        #pragma unroll
        for (int of = 0; of < 3; ++of)
            #pragma unroll
            for (int i = 0; i < 16; ++i) acc[of][i] = 0.0f;
        #pragma unroll
        for (int kc = 0; kc < 5; ++kc) {
            short8v a = *(const short8v*)&Es[(nf * 32 + m32) * 88 + kc * 16 + H * 8];
            #pragma unroll
            for (int of = 0; of < 3; ++of) {
                short8v bf = *(const short8v*)&W3p[(colbase + of * 32 + m32) * 88 + kc * 16 + H * 8];
                acc[of] = __builtin_amdgcn_mfma_f32_32x32x16_bf16(a, bf, acc[of], 0, 0, 0);
            }
        }
        #pragma unroll
        for (int of = 0; of < 3; ++of) {
            int col0 = colbase + of * 32;
            int mi = col0 >> 7, e0 = col0 & 127;
            unsigned short* dst = (mi == 0) ? Qb : (mi == 1) ? Kb : Vn;
            #pragma unroll
            for (int r = 0; r < 16; ++r) {
                int n = n0 + nf * 32 + (r & 3) + 8 * (r >> 2) + 4 * H;
                dst[((size_t)b * N_ + n) * DI_ + e0 + m32] = f2bf(acc[of][r]);
            }
        }
    }
}

// ---------------------------------------------------------------------------
// Kernel 2: Kb -> Ksw tiles [32k][16 chunks], image pos p = c ^ (r&15).
// block handles 2 tiles (64 k rows); grid 16 x 36.
// ---------------------------------------------------------------------------
__global__ __launch_bounds__(256) void repackK_kernel(
    const unsigned short* __restrict__ Kb, unsigned short* __restrict__ Ksw)
{
    const int blk = blockIdx.x;
    const int b = blk / 36, g2 = blk - b * 36;
    const int t = threadIdx.x;
    const size_t src = ((size_t)b * N_ + g2 * 64) * DI_;
    const size_t dst = ((size_t)b * NKT_ + g2 * 2) * KTSZ_;
    #pragma unroll
    for (int i = 0; i < 4; ++i) {
        int o = i * 256 + t;             // chunk in 2-tile group, 0..1023
        int r = (o >> 4) & 31, p = o & 15;
        int c = p ^ (r & 15);
        int row = (o >> 9) * 32 + r;     // source k row 0..63
        *(int4*)(Ksw + dst + (size_t)o * 8) = *(const int4*)(Kb + src + row * DI_ + c * 8);
    }
}

// ---------------------------------------------------------------------------
// Kernel 3: Zg[b][k] = sum_q exp2(S2 * dot(Q,K)) ; grid 16b x 18qt x 2kh = 576
// S = Q.K^T : A = qreg (regs), B = K-frag (LDS). C col = k -> in-lane q-sum.
// 256 thr (4 waves = wq), k-half loop 36 tiles of 32.
// ---------------------------------------------------------------------------
__global__ __launch_bounds__(256, 4) void zsum_kernel(
    const unsigned short* __restrict__ Qb, const unsigned short* __restrict__ Ksw,
    float* __restrict__ Zg)
{
    __shared__ unsigned short Ks[2][KTSZ_];
    __shared__ float Zacc[1152];
    const int t = threadIdx.x;
    const int blk = blockIdx.x;
    const int b   = 2 * (blk & 7) + ((blk >> 3) & 1);
    const int rest = blk >> 4;           // 0..35
    const int qt = rest % 18, kh = rest / 18;
    const int q0 = qt * 128;
    const int l = t & 63, w = t >> 6;
    const int m32 = l & 31, H = l >> 5;

    for (int i = t; i < 1152; i += 256) Zacc[i] = 0.0f;

    short8v qreg[8];   // A-frag [32q x 16e] per ec: lane row q = m32
    {
        const unsigned short* qp = Qb + ((size_t)b * N_ + q0 + w * 32 + m32) * DI_ + H * 8;
        #pragma unroll
        for (int ec = 0; ec < 8; ++ec) qreg[ec] = *(const short8v*)(qp + ec * 16);
    }
    const unsigned short* kswb = Ksw + ((size_t)b * NKT_ + kh * 36) * KTSZ_;
    stage_k(kswb, &Ks[0][0], w, l);
    asm volatile("s_waitcnt vmcnt(0)" ::: "memory");
    __syncthreads();

    for (int kt = 0; kt < 36; ++kt) {
        if (kt + 1 < 36) stage_k(kswb + (size_t)(kt + 1) * KTSZ_, &Ks[(kt + 1) & 1][0], w, l);
        const unsigned short* kb = &Ks[kt & 1][0];
        f32x16 sa, sb;
        #pragma unroll
        for (int i = 0; i < 16; ++i) { sa[i] = 0.0f; sb[i] = 0.0f; }
        __builtin_amdgcn_s_setprio(1);
        #pragma unroll
        for (int ec = 0; ec < 8; ++ec) {
            // B-frag [16e x 32k]: lane col k = m32, rows e contiguous
            short8v bk = *(const short8v*)&kb[m32 * DI_ + (((ec * 2 + H) ^ (m32 & 15)) * 8)];
            if (ec & 1) sb = __builtin_amdgcn_mfma_f32_32x32x16_bf16(qreg[ec], bk, sb, 0, 0, 0);
            else        sa = __builtin_amdgcn_mfma_f32_32x32x16_bf16(qreg[ec], bk, sa, 0, 0, 0);
        }
        __builtin_amdgcn_s_setprio(0);
        float zl = 0.0f;
        #pragma unroll
        for (int r = 0; r < 16; ++r) zl += exp2f((sa[r] + sb[r]) * S2_);
        atomicAdd(&Zacc[kt * 32 + m32], zl);
        asm volatile("s_waitcnt vmcnt(0)" ::: "memory");
        __syncthreads();
    }
    for (int i = t; i < 1152; i += 256)
        atomicAdd(&Zg[(size_t)b * N_ + kh * 1152 + i], Zacc[i]);
}

// ---------------------------------------------------------------------------
// Kernel 4: Vn + Zg -> Vsw tiles [128 d][pitch 36] (k at [d*36+k], /Z folded)
// grid 16 x 72 (one 32k tile per block).
// ---------------------------------------------------------------------------
__global__ __launch_bounds__(256) void repackV_kernel(
    const unsigned short* __restrict__ Vn, const float* __restrict__ Zg,
    unsigned short* __restrict__ Vsw)
{
    __shared__ unsigned short Vstg[32 * 132];
    __shared__ float zinv[32];
    const int blk = blockIdx.x;
    const int b = blk / NKT_, kt = blk - b * NKT_;
    const int t = threadIdx.x;
    const int k0 = kt * 32;
    {
        const int k = t >> 3, c = (t & 7) * 16;
        const unsigned short* src = Vn + ((size_t)b * N_ + k0 + k) * DI_ + c;
        *(int4*)&Vstg[k * 132 + c]     = *(const int4*)(src);
        *(int4*)&Vstg[k * 132 + c + 8] = *(const int4*)(src + 8);
    }
    if (t < 32) zinv[t] = 1.0f / Zg[(size_t)b * N_ + k0 + t];
    __syncthreads();
    unsigned short* dstt = Vsw + ((size_t)b * NKT_ + kt) * VTSZ_;
    const int d = t & 127, part = t >> 7;
    #pragma unroll
    for (int g = 0; g < 4; ++g) {
        unsigned short sv[4];
        #pragma unroll
        for (int j = 0; j < 4; ++j) {
            int k = part * 16 + g * 4 + j;
            sv[j] = f2bf(bf2f(Vstg[k * 132 + d]) * zinv[k]);
        }
        *(int2*)(dstt + d * 36 + part * 16 + g * 4) = *(const int2*)sv;
    }
    if (part == 1) {   // zero pad cols 32..35
        unsigned short z4[4] = {0, 0, 0, 0};
        *(int2*)(dstt + d * 36 + 32) = *(const int2*)z4;
    }
}

// ---------------------------------------------------------------------------
// Kernel 5: partial Out^T = Vz^T . P, P = exp2(S2*S) recomputed (S^T = K.Q^T)
// grid 16b x 18qt x 2kh = 576, 256 thr (4 q-waves, 32q x 128d per wave).
// kh0 -> d_out, kh1 -> Opart; reduce kernel adds.
// ---------------------------------------------------------------------------
__global__ __launch_bounds__(256, 3) void attn_kernel(
    const unsigned short* __restrict__ Qb, const unsigned short* __restrict__ Ksw,
    const unsigned short* __restrict__ Vsw,
    float* __restrict__ O0, float* __restrict__ O1)
{
    __shared__ unsigned short Ks[2][KTSZ_];
    __shared__ unsigned short Vs[2][VTSZ_];
    const int t = threadIdx.x;
    const int blk = blockIdx.x;
    const int b   = 2 * (blk & 7) + ((blk >> 3) & 1);
    const int rest = blk >> 4;
    const int qt = rest % 18, kh = rest / 18;
    const int q0 = qt * 128;
    const int l = t & 63, w = t >> 6;
    const int m32 = l & 31, H = l >> 5;

    short8v qreg[8];   // B-frag [16e x 32q]: lane col q = m32
    {
        const unsigned short* qp = Qb + ((size_t)b * N_ + q0 + w * 32 + m32) * DI_ + H * 8;
        #pragma unroll
        for (int ec = 0; ec < 8; ++ec) qreg[ec] = *(const short8v*)(qp + ec * 16);
    }
    f32x16 oacc[4];
    #pragma unroll
    for (int df = 0; df < 4; ++df)
        #pragma unroll
        for (int i = 0; i < 16; ++i) oacc[df][i] = 0.0f;

    const unsigned short* kswb = Ksw + ((size_t)b * NKT_ + kh * 36) * KTSZ_;
    const unsigned short* vswb = Vsw + ((size_t)b * NKT_ + kh * 36) * VTSZ_;
    stage_k(kswb, &Ks[0][0], w, l);
    stage_v(vswb, &Vs[0][0], w, l, t);
    asm volatile("s_waitcnt vmcnt(0)" ::: "memory");
    __syncthreads();

    for (int kt = 0; kt < 36; ++kt) {
        if (kt + 1 < 36) {
            stage_k(kswb + (size_t)(kt + 1) * KTSZ_, &Ks[(kt + 1) & 1][0], w, l);
            stage_v(vswb + (size_t)(kt + 1) * VTSZ_, &Vs[(kt + 1) & 1][0], w, l, t);
        }
        const unsigned short* kb = &Ks[kt & 1][0];
        const unsigned short* vb = &Vs[kt & 1][0];

        // ---- S^T = K.Q^T : A = K-frag [32k x 16e] (lane row k = m32) ----
        f32x16 sa, sb;
        #pragma unroll
        for (int i = 0; i < 16; ++i) { sa[i] = 0.0f; sb[i] = 0.0f; }
        __builtin_amdgcn_s_setprio(1);
        #pragma unroll
        for (int ec = 0; ec < 8; ++ec) {
            short8v ak = *(const short8v*)&kb[m32 * DI_ + (((ec * 2 + H) ^ (m32 & 15)) * 8)];
            if (ec & 1) sb = __builtin_amdgcn_mfma_f32_32x32x16_bf16(ak, qreg[ec], sb, 0, 0, 0);
            else        sa = __builtin_amdgcn_mfma_f32_32x32x16_bf16(ak, qreg[ec], sa, 0, 0, 0);
        }
        __builtin_amdgcn_s_setprio(0);

        // ---- P = exp2, pack to bf16 B-frags [16k x 32q] ----
        float p[16];
        #pragma unroll
        for (int r = 0; r < 16; ++r) p[r] = exp2f((sa[r] + sb[r]) * S2_);
        unsigned c0[4], c1[4];
        #pragma unroll
        for (int m = 0; m < 4; ++m) {
            c0[m] = cvtpk_bf16(p[4 * m],     p[4 * m + 1]);
            c1[m] = cvtpk_bf16(p[4 * m + 2], p[4 * m + 3]);
        }
        short8v pB[2];
        #pragma unroll
        for (int kq = 0; kq < 2; ++kq) {
            unsigned d0 = c0[2 * kq], d2 = c0[2 * kq + 1];
            plswap(d0, d2);
            unsigned d1 = c1[2 * kq], d3 = c1[2 * kq + 1];
            plswap(d1, d3);
            int4 t4; t4.x = (int)d0; t4.y = (int)d1; t4.z = (int)d2; t4.w = (int)d3;
            pB[kq] = __builtin_bit_cast(short8v, t4);
        }

        // ---- O^T += Vz^T . P : A = Vz-frag [32d x 16k] ----
        __builtin_amdgcn_s_setprio(1);
        #pragma unroll
        for (int df = 0; df < 4; ++df) {
            const int vo = (df * 32 + m32) * 36;
            #pragma unroll
            for (int kq = 0; kq < 2; ++kq) {
                V8u u;
                u.v4[0] = *(const short4v*)&vb[vo + kq * 16 + H * 8];
                u.v4[1] = *(const short4v*)&vb[vo + kq * 16 + H * 8 + 4];
                oacc[df] = __builtin_amdgcn_mfma_f32_32x32x16_bf16(u.v8, pB[kq], oacc[df], 0, 0, 0);
            }
        }
        __builtin_amdgcn_s_setprio(0);
        asm volatile("s_waitcnt vmcnt(0)" ::: "memory");
        __syncthreads();
    }

    float* outp = (kh == 0 ? O0 : O1) + ((size_t)b * N_ + q0 + w * 32 + m32) * DI_;
    #pragma unroll
    for (int df = 0; df < 4; ++df)
        #pragma unroll
        for (int r = 0; r < 16; ++r) {
            int d = df * 32 + (r & 3) + 8 * (r >> 2) + 4 * H;
            outp[d] = oacc[df][r];
        }
}

// ---------------------------------------------------------------------------
// Kernel 6: out += Opart  (4.7M f32)
// ---------------------------------------------------------------------------
__global__ __launch_bounds__(256) void reduce_kernel(
    float* __restrict__ out, const float* __restrict__ part)
{
    const size_t stride = (size_t)1152 * 256;
    for (size_t idx = (size_t)blockIdx.x * 256 + threadIdx.x; idx < 1179648; idx += stride) {
        float4 a = ((float4*)out)[idx];
        float4 c = ((const float4*)part)[idx];
        a.x += c.x; a.y += c.y; a.z += c.z; a.w += c.w;
        ((float4*)out)[idx] = a;
    }
}

// ---------------------------------------------------------------------------
extern "C" void kernel_launch(void* const* d_in, const int* in_sizes, int n_in,
                              void* d_out, int out_size, void* d_ws, size_t ws_size,
                              hipStream_t stream)
{
    const float* x  = (const float*)d_in[0];
    const float* Wq = (const float*)d_in[1];
    const float* Wk = (const float*)d_in[2];
    const float* Wv = (const float*)d_in[3];

    unsigned short* Qb  = (unsigned short*)d_ws;            // [B][N][128]
    unsigned short* Kb  = Qb  + NB_;                        // [B][N][128]
    unsigned short* Vn  = Kb  + NB_;                        // [B][N][128]
    unsigned short* Ksw = Vn  + NB_;                        // [B][72] K tiles
    unsigned short* Vsw = Ksw + NB_;                        // [B][72] V tiles (pitch 36)
    unsigned short* W3p = Vsw + (size_t)B_ * NKT_ * VTSZ_;  // [384][88]
    float*          Zg  = (float*)(W3p + 384 * 88);         // [B][N]
    float*          Op  = Zg + (size_t)B_ * N_;             // [B][N][128] partial
    float* out = (float*)d_out;

    hipMemsetAsync(Zg, 0, (size_t)B_ * N_ * sizeof(float), stream);
    wprep_kernel  <<<1,    256, 0, stream>>>(Wq, Wk, Wv, W3p);
    qkv_kernel    <<<288,  256, 0, stream>>>(x, W3p, Qb, Kb, Vn);
    repackK_kernel<<<576,  256, 0, stream>>>(Kb, Ksw);
    zsum_kernel   <<<576,  256, 0, stream>>>(Qb, Ksw, Zg);
    repackV_kernel<<<1152, 256, 0, stream>>>(Vn, Zg, Vsw);
    attn_kernel   <<<576,  256, 0, stream>>>(Qb, Ksw, Vsw, out, Op);
    reduce_kernel <<<1152, 256, 0, stream>>>(out, Op);
}

// Round 6
// 154.669 us; speedup vs baseline: 1.5225x; 1.2572x over previous
//
#include <hip/hip_runtime.h>
#include <cstdint>

#define B_    16
#define D_    64
#define N_    2304
#define DI_   128
#define S2_   0.12751875732488788f    // (1/sqrt(128)) * log2(e)  -- folded into Q
#define NB_   ((size_t)B_ * N_ * DI_)
#define KTSZ_ 4096                    // K tile: 32k x 128e shorts (swizzled image)
#define VTSZ_ 5120                    // V tile: 128d x 40k shorts (16B-aligned pitch)
#define NKT_  72                      // 32-row k tiles per batch
#define NKH_  18                      // k tiles per kh quarter
#define OF4_  1179648                 // float4s per partial (= NB_/4)

typedef __attribute__((ext_vector_type(8)))  short short8v;
typedef __attribute__((ext_vector_type(16))) float f32x16;

#if defined(__has_builtin)
#if __has_builtin(__builtin_amdgcn_exp2f)
#define EXP2(x) __builtin_amdgcn_exp2f(x)
#else
#define EXP2(x) exp2f(x)
#endif
#else
#define EXP2(x) exp2f(x)
#endif

__device__ __forceinline__ unsigned short f2bf(float f) {
    unsigned u = __builtin_bit_cast(unsigned, f);
    u = (u + 0x7FFFu + ((u >> 16) & 1u)) >> 16;
    return (unsigned short)u;
}
__device__ __forceinline__ float bf2f(unsigned short h) {
    unsigned u = ((unsigned)h) << 16;
    return __builtin_bit_cast(float, u);
}
__device__ __forceinline__ unsigned cvtpk_bf16(float lo, float hi) {
    unsigned r;
    asm volatile("v_cvt_pk_bf16_f32 %0, %1, %2" : "=v"(r) : "v"(lo), "v"(hi));
    return r;
}
__device__ __forceinline__ void plswap(unsigned &a, unsigned &b) {
    asm volatile("v_permlane32_swap_b32 %0, %1" : "+v"(a), "+v"(b));
}

// DMA: wave-uniform LDS base + lane*16B; per-lane global src.
__device__ __forceinline__ void stage_k(const unsigned short* g,
                                        unsigned short* l_, int w, int ln) {
    #pragma unroll
    for (int i = 0; i < 2; ++i)
        __builtin_amdgcn_global_load_lds(
            (const __attribute__((address_space(1))) void*)(g + i * 2048 + w * 512 + ln * 8),
            (__attribute__((address_space(3))) void*)(l_ + i * 2048 + w * 512), 16, 0, 0);
}
__device__ __forceinline__ void stage_v(const unsigned short* g,
                                        unsigned short* l_, int w, int ln, int t) {
    #pragma unroll
    for (int i = 0; i < 2; ++i)
        __builtin_amdgcn_global_load_lds(
            (const __attribute__((address_space(1))) void*)(g + i * 2048 + w * 512 + ln * 8),
            (__attribute__((address_space(3))) void*)(l_ + i * 2048 + w * 512), 16, 0, 0);
    if (t < 128)
        __builtin_amdgcn_global_load_lds(
            (const __attribute__((address_space(1))) void*)(g + 4096 + w * 512 + ln * 8),
            (__attribute__((address_space(3))) void*)(l_ + 4096 + w * 512), 16, 0, 0);
}

// ---------------------------------------------------------------------------
// Kernel 0: block0 -> W3p [384][88] bf16; blocks 1..144 -> zero Zg (36864 f32)
// ---------------------------------------------------------------------------
__global__ __launch_bounds__(256) void prep_kernel(
    const float* __restrict__ Wq, const float* __restrict__ Wk,
    const float* __restrict__ Wv, unsigned short* __restrict__ W3p,
    float* __restrict__ Zg)
{
    const int t = threadIdx.x;
    if (blockIdx.x == 0) {
        for (int r = t; r < 384; r += 256) {
            const float* src = (r < 128) ? (Wq + r * 66)
                             : (r < 256) ? (Wk + (r - 128) * 66) : (Wv + (r - 256) * 66);
            for (int c = 0; c < 66; ++c) W3p[r * 88 + c] = f2bf(src[c]);
            for (int c = 66; c < 88; ++c) W3p[r * 88 + c] = 0;
        }
    } else {
        Zg[(blockIdx.x - 1) * 256 + t] = 0.0f;
    }
}

// ---------------------------------------------------------------------------
// Kernel 1: QKV projection via MFMA.  Q scaled by S2_ at store time.
// K written directly as swizzled tile images (repackK fused away).
// grid 16b x 18nt(128), 256 thr.
// ---------------------------------------------------------------------------
__global__ __launch_bounds__(256) void qkv_kernel(
    const float* __restrict__ x, const unsigned short* __restrict__ W3p,
    unsigned short* __restrict__ Qb, unsigned short* __restrict__ Ksw,
    unsigned short* __restrict__ Vn)
{
    __shared__ unsigned short Es[128 * 88];
    const int t = threadIdx.x;
    const int b = blockIdx.x / 18, nt = blockIdx.x - b * 18;
    const int n0 = nt * 128;

    {   // x -> Es transposed bf16 (cols 0..63)
        const int d = t & 63, q4 = t >> 6;
        const float* xp = x + ((size_t)b * D_ + d) * N_ + n0 + q4 * 32;
        float xv[32];
        #pragma unroll
        for (int i = 0; i < 8; ++i) *(float4*)(xv + 4 * i) = *(const float4*)(xp + 4 * i);
        #pragma unroll
        for (int i = 0; i < 32; ++i) Es[(q4 * 32 + i) * 88 + d] = f2bf(xv[i]);
    }
    if (t < 128) {  // coords + zero pad
        int n = n0 + t;
        int ix = n / 48, iy = n - ix * 48;
        Es[t * 88 + 64] = f2bf(-1.0f + ((float)ix + 0.5f) * (2.0f / 48.0f));
        Es[t * 88 + 65] = f2bf(-1.0f + ((float)iy + 0.5f) * (2.0f / 48.0f));
        #pragma unroll
        for (int m = 0; m < 11; ++m) *(unsigned*)&Es[t * 88 + 66 + 2 * m] = 0;
    }
    __syncthreads();

    const int l = t & 63, w = t >> 6;
    const int m32 = l & 31, H = l >> 5;
    const int colbase = w * 96;
    #pragma unroll
    for (int nf = 0; nf < 4; ++nf) {
        f32x16 acc[3];
        #pragma unroll
        for (int of = 0; of < 3; ++of)
            #pragma unroll
            for (int i = 0; i < 16; ++i) acc[of][i] = 0.0f;
        #pragma unroll
        for (int kc = 0; kc < 5; ++kc) {
            short8v a = *(const short8v*)&Es[(nf * 32 + m32) * 88 + kc * 16 + H * 8];
            #pragma unroll
            for (int of = 0; of < 3; ++of) {
                short8v bf = *(const short8v*)&W3p[(colbase + of * 32 + m32) * 88 + kc * 16 + H * 8];
                acc[of] = __builtin_amdgcn_mfma_f32_32x32x16_bf16(a, bf, acc[of], 0, 0, 0);
            }
        }
        #pragma unroll
        for (int of = 0; of < 3; ++of) {
            const int col0 = colbase + of * 32;
            const int mi = col0 >> 7, e0 = col0 & 127;
            const int e = e0 + m32;
            if (mi == 0) {          // Q rows, scaled
                #pragma unroll
                for (int r = 0; r < 16; ++r) {
                    int n = n0 + nf * 32 + (r & 3) + 8 * (r >> 2) + 4 * H;
                    Qb[((size_t)b * N_ + n) * DI_ + e] = f2bf(acc[of][r] * S2_);
                }
            } else if (mi == 1) {   // K -> swizzled tile image
                const size_t tbase = ((size_t)b * NKT_ + nt * 4 + nf) * KTSZ_;
                const int cx = e >> 3, ei = e & 7;
                #pragma unroll
                for (int r = 0; r < 16; ++r) {
                    int rr = (r & 3) + 8 * (r >> 2) + 4 * H;
                    Ksw[tbase + rr * 128 + ((cx ^ (rr & 15)) * 8) + ei] = f2bf(acc[of][r]);
                }
            } else {                // V rows
                #pragma unroll
                for (int r = 0; r < 16; ++r) {
                    int n = n0 + nf * 32 + (r & 3) + 8 * (r >> 2) + 4 * H;
                    Vn[((size_t)b * N_ + n) * DI_ + e] = f2bf(acc[of][r]);
                }
            }
        }
    }
}

// ---------------------------------------------------------------------------
// Kernel 2: Zg[b][k] += sum_q exp2(dot(Q',K))  over this block's q-tile.
// grid 1152 (16b x 18qt x 4kh), 256 thr; 18 k-tiles of 32, unrolled x2.
// ---------------------------------------------------------------------------
__global__ __launch_bounds__(256, 4) void zsum_kernel(
    const unsigned short* __restrict__ Qb, const unsigned short* __restrict__ Ksw,
    float* __restrict__ Zg)
{
    __shared__ unsigned short Ks0[KTSZ_], Ks1[KTSZ_];
    __shared__ float Zacc[576];
    const int t = threadIdx.x;
    const int blk = blockIdx.x;
    const int b = 2 * (blk & 7) + ((blk >> 3) & 1);
    const int rest = blk >> 4;           // 0..71
    const int qt = rest % 18, kh = rest / 18;
    const int q0 = qt * 128;
    const int l = t & 63, w = t >> 6;
    const int m32 = l & 31, H = l >> 5;

    for (int i = t; i < 576; i += 256) Zacc[i] = 0.0f;

    short8v qreg[8];
    {
        const unsigned short* qp = Qb + ((size_t)b * N_ + q0 + w * 32 + m32) * DI_ + H * 8;
        #pragma unroll
        for (int ec = 0; ec < 8; ++ec) qreg[ec] = *(const short8v*)(qp + ec * 16);
    }
    int ka[8];
    #pragma unroll
    for (int ec = 0; ec < 8; ++ec)
        ka[ec] = m32 * 128 + (((ec * 2 + H) ^ (m32 & 15)) * 8);

    const unsigned short* kswb = Ksw + ((size_t)b * NKT_ + kh * NKH_) * KTSZ_;
    stage_k(kswb, Ks0, w, l);
    asm volatile("s_waitcnt vmcnt(0)" ::: "memory");
    __syncthreads();

#define ZSUM_STEP(KB, KTC)                                                     \
    {                                                                          \
        f32x16 sa, sb;                                                         \
        _Pragma("unroll") for (int i = 0; i < 16; ++i) { sa[i] = 0.f; sb[i] = 0.f; } \
        __builtin_amdgcn_s_setprio(1);                                         \
        _Pragma("unroll") for (int ec = 0; ec < 8; ++ec) {                     \
            short8v bk = *(const short8v*)&(KB)[ka[ec]];                       \
            if (ec & 1) sb = __builtin_amdgcn_mfma_f32_32x32x16_bf16(qreg[ec], bk, sb, 0, 0, 0); \
            else        sa = __builtin_amdgcn_mfma_f32_32x32x16_bf16(qreg[ec], bk, sa, 0, 0, 0); \
        }                                                                      \
        __builtin_amdgcn_s_setprio(0);                                         \
        float zl = 0.0f;                                                       \
        _Pragma("unroll") for (int r = 0; r < 16; ++r) zl += EXP2(sa[r] + sb[r]); \
        atomicAdd(&Zacc[(KTC) * 32 + m32], zl);                                \
        asm volatile("s_waitcnt vmcnt(0)" ::: "memory");                       \
        __syncthreads();                                                       \
    }

    for (int kt = 0; kt < NKH_; kt += 2) {
        stage_k(kswb + (size_t)(kt + 1) * KTSZ_, Ks1, w, l);
        ZSUM_STEP(Ks0, kt);
        if (kt + 2 < NKH_) stage_k(kswb + (size_t)(kt + 2) * KTSZ_, Ks0, w, l);
        ZSUM_STEP(Ks1, kt + 1);
    }
    for (int i = t; i < 576; i += 256)
        atomicAdd(&Zg[(size_t)b * N_ + kh * 576 + i], Zacc[i]);
}

// ---------------------------------------------------------------------------
// Kernel 3: Vn + Zg -> Vsw tiles [128 d][pitch 40] (/Z folded)
// grid 16 x 72, 256 thr.
// ---------------------------------------------------------------------------
__global__ __launch_bounds__(256) void repackV_kernel(
    const unsigned short* __restrict__ Vn, const float* __restrict__ Zg,
    unsigned short* __restrict__ Vsw)
{
    __shared__ unsigned short Vstg[32 * 132];
    __shared__ float zinv[32];
    const int blk = blockIdx.x;
    const int b = blk / NKT_, kt = blk - b * NKT_;
    const int t = threadIdx.x;
    const int k0 = kt * 32;
    {
        const int k = t >> 3, c = (t & 7) * 16;
        const unsigned short* src = Vn + ((size_t)b * N_ + k0 + k) * DI_ + c;
        *(int4*)&Vstg[k * 132 + c]     = *(const int4*)(src);
        *(int4*)&Vstg[k * 132 + c + 8] = *(const int4*)(src + 8);
    }
    if (t < 32) zinv[t] = 1.0f / Zg[(size_t)b * N_ + k0 + t];
    __syncthreads();
    unsigned short* dstt = Vsw + ((size_t)b * NKT_ + kt) * VTSZ_;
    const int d = t & 127, part = t >> 7;
    #pragma unroll
    for (int g = 0; g < 4; ++g) {
        unsigned short sv[4];
        #pragma unroll
        for (int j = 0; j < 4; ++j) {
            int k = part * 16 + g * 4 + j;
            sv[j] = f2bf(bf2f(Vstg[k * 132 + d]) * zinv[k]);
        }
        *(int2*)(dstt + d * 40 + part * 16 + g * 4) = *(const int2*)sv;
    }
}

// ---------------------------------------------------------------------------
// Kernel 4: partial Out^T = Vz^T . P over one kh quarter.
// grid 1152 (16b x 18qt x 4kh), 256 thr; kh0 -> out, kh1..3 -> Op[kh-1].
// ---------------------------------------------------------------------------
__global__ __launch_bounds__(256, 3) void attn_kernel(
    const unsigned short* __restrict__ Qb, const unsigned short* __restrict__ Ksw,
    const unsigned short* __restrict__ Vsw,
    float* __restrict__ O0, float* __restrict__ Op)
{
    __shared__ unsigned short Ks0[KTSZ_], Ks1[KTSZ_];
    __shared__ unsigned short Vs0[VTSZ_], Vs1[VTSZ_];
    const int t = threadIdx.x;
    const int blk = blockIdx.x;
    const int b = 2 * (blk & 7) + ((blk >> 3) & 1);
    const int rest = blk >> 4;
    const int qt = rest % 18, kh = rest / 18;
    const int q0 = qt * 128;
    const int l = t & 63, w = t >> 6;
    const int m32 = l & 31, H = l >> 5;

    short8v qreg[8];
    {
        const unsigned short* qp = Qb + ((size_t)b * N_ + q0 + w * 32 + m32) * DI_ + H * 8;
        #pragma unroll
        for (int ec = 0; ec < 8; ++ec) qreg[ec] = *(const short8v*)(qp + ec * 16);
    }
    f32x16 oacc[4];
    #pragma unroll
    for (int df = 0; df < 4; ++df)
        #pragma unroll
        for (int i = 0; i < 16; ++i) oacc[df][i] = 0.0f;

    int ka[8];
    #pragma unroll
    for (int ec = 0; ec < 8; ++ec)
        ka[ec] = m32 * 128 + (((ec * 2 + H) ^ (m32 & 15)) * 8);
    const int vb0 = m32 * 40 + H * 8;

    const unsigned short* kswb = Ksw + ((size_t)b * NKT_ + kh * NKH_) * KTSZ_;
    const unsigned short* vswb = Vsw + ((size_t)b * NKT_ + kh * NKH_) * VTSZ_;
    stage_k(kswb, Ks0, w, l);
    stage_v(vswb, Vs0, w, l, t);
    asm volatile("s_waitcnt vmcnt(0)" ::: "memory");
    __syncthreads();

#define ATTN_STEP(KB, VB)                                                      \
    {                                                                          \
        f32x16 sa, sb;                                                         \
        _Pragma("unroll") for (int i = 0; i < 16; ++i) { sa[i] = 0.f; sb[i] = 0.f; } \
        __builtin_amdgcn_s_setprio(1);                                         \
        _Pragma("unroll") for (int ec = 0; ec < 8; ++ec) {                     \
            short8v ak = *(const short8v*)&(KB)[ka[ec]];                       \
            if (ec & 1) sb = __builtin_amdgcn_mfma_f32_32x32x16_bf16(ak, qreg[ec], sb, 0, 0, 0); \
            else        sa = __builtin_amdgcn_mfma_f32_32x32x16_bf16(ak, qreg[ec], sa, 0, 0, 0); \
        }                                                                      \
        __builtin_amdgcn_s_setprio(0);                                         \
        float p[16];                                                           \
        _Pragma("unroll") for (int r = 0; r < 16; ++r) p[r] = EXP2(sa[r] + sb[r]); \
        unsigned c0[4], c1[4];                                                 \
        _Pragma("unroll") for (int m = 0; m < 4; ++m) {                        \
            c0[m] = cvtpk_bf16(p[4 * m],     p[4 * m + 1]);                    \
            c1[m] = cvtpk_bf16(p[4 * m + 2], p[4 * m + 3]);                    \
        }                                                                      \
        short8v pB[2];                                                         \
        _Pragma("unroll") for (int kq = 0; kq < 2; ++kq) {                     \
            unsigned d0 = c0[2 * kq], d2 = c0[2 * kq + 1]; plswap(d0, d2);     \
            unsigned d1 = c1[2 * kq], d3 = c1[2 * kq + 1]; plswap(d1, d3);     \
            int4 t4; t4.x = (int)d0; t4.y = (int)d1; t4.z = (int)d2; t4.w = (int)d3; \
            pB[kq] = __builtin_bit_cast(short8v, t4);                          \
        }                                                                      \
        __builtin_amdgcn_s_setprio(1);                                         \
        _Pragma("unroll") for (int df = 0; df < 4; ++df) {                     \
            _Pragma("unroll") for (int kq = 0; kq < 2; ++kq) {                 \
                short8v av = *(const short8v*)&(VB)[vb0 + df * 1280 + kq * 16]; \
                oacc[df] = __builtin_amdgcn_mfma_f32_32x32x16_bf16(av, pB[kq], oacc[df], 0, 0, 0); \
            }                                                                  \
        }                                                                      \
        __builtin_amdgcn_s_setprio(0);                                         \
        asm volatile("s_waitcnt vmcnt(0)" ::: "memory");                       \
        __syncthreads();                                                       \
    }

    for (int kt = 0; kt < NKH_; kt += 2) {
        stage_k(kswb + (size_t)(kt + 1) * KTSZ_, Ks1, w, l);
        stage_v(vswb + (size_t)(kt + 1) * VTSZ_, Vs1, w, l, t);
        ATTN_STEP(Ks0, Vs0);
        if (kt + 2 < NKH_) {
            stage_k(kswb + (size_t)(kt + 2) * KTSZ_, Ks0, w, l);
            stage_v(vswb + (size_t)(kt + 2) * VTSZ_, Vs0, w, l, t);
        }
        ATTN_STEP(Ks1, Vs1);
    }

    float* outp = (kh == 0 ? O0 : (Op + (size_t)(kh - 1) * NB_))
                + ((size_t)b * N_ + q0 + w * 32 + m32) * DI_;
    #pragma unroll
    for (int df = 0; df < 4; ++df)
        #pragma unroll
        for (int r = 0; r < 16; ++r) {
            int d = df * 32 + (r & 3) + 8 * (r >> 2) + 4 * H;
            outp[d] = oacc[df][r];
        }
}

// ---------------------------------------------------------------------------
// Kernel 5: out += Op0 + Op1 + Op2.  One float4/thread, grid 4608 x 256
// (4608*256 = 1179648 = OF4_ float4s = NB_ floats).  Partial stride = OF4_.
// ---------------------------------------------------------------------------
__global__ __launch_bounds__(256) void reduce_kernel(
    float* __restrict__ out, const float* __restrict__ part)
{
    const size_t idx = (size_t)blockIdx.x * 256 + threadIdx.x;
    float4 p0 = ((const float4*)part)[idx];
    float4 p1 = ((const float4*)part)[idx + (size_t)OF4_];
    float4 p2 = ((const float4*)part)[idx + 2 * (size_t)OF4_];
    float4 o  = ((float4*)out)[idx];
    o.x += p0.x + p1.x + p2.x;
    o.y += p0.y + p1.y + p2.y;
    o.z += p0.z + p1.z + p2.z;
    o.w += p0.w + p1.w + p2.w;
    ((float4*)out)[idx] = o;
}

// ---------------------------------------------------------------------------
extern "C" void kernel_launch(void* const* d_in, const int* in_sizes, int n_in,
                              void* d_out, int out_size, void* d_ws, size_t ws_size,
                              hipStream_t stream)
{
    const float* x  = (const float*)d_in[0];
    const float* Wq = (const float*)d_in[1];
    const float* Wk = (const float*)d_in[2];
    const float* Wv = (const float*)d_in[3];

    // Layout (87.5 MB total). Vn is aliased into the head of the Op region:
    // Vn is dead after repackV completes; Op is first written by attn, which
    // launches after repackV (stream-ordered) — no lifetime overlap.
    unsigned short* Qb  = (unsigned short*)d_ws;            // [B][N][128] (pre-scaled)
    unsigned short* Ksw = Qb  + NB_;                        // [B][72] swizzled K tiles
    unsigned short* Vsw = Ksw + NB_;                        // [B][72] V tiles pitch 40
    unsigned short* W3p = Vsw + (size_t)B_ * NKT_ * VTSZ_;  // [384][88]
    float*          Zg  = (float*)(W3p + 384 * 88);         // [B][N]
    float*          Op  = Zg + (size_t)B_ * N_;             // 3 x [B][N][128] partials
    unsigned short* Vn  = (unsigned short*)Op;              // [B][N][128] (aliased)
    float* out = (float*)d_out;

    prep_kernel   <<<145,  256, 0, stream>>>(Wq, Wk, Wv, W3p, Zg);
    qkv_kernel    <<<288,  256, 0, stream>>>(x, W3p, Qb, Ksw, Vn);
    zsum_kernel   <<<1152, 256, 0, stream>>>(Qb, Ksw, Zg);
    repackV_kernel<<<1152, 256, 0, stream>>>(Vn, Zg, Vsw);
    attn_kernel   <<<1152, 256, 0, stream>>>(Qb, Ksw, Vsw, out, Op);
    reduce_kernel <<<4608, 256, 0, stream>>>(out, Op);
}

// Round 7
// 154.564 us; speedup vs baseline: 1.5236x; 1.0007x over previous
//
#include <hip/hip_runtime.h>
#include <cstdint>

#define B_    16
#define D_    64
#define N_    2304
#define DI_   128
#define S2_   0.12751875732488788f    // (1/sqrt(128)) * log2(e)  -- folded into Q
#define NB_   ((size_t)B_ * N_ * DI_)
#define KTSZ_ 4096                    // K tile: 32k x 128e shorts (swizzled image)
#define VTSZ_ 5120                    // V tile: 128d x 40k shorts (16B-aligned pitch)
#define NKT_  72                      // 32-row k tiles per batch
#define NKH_  18                      // k tiles per kh quarter
#define OF4_  1179648                 // float4s per partial (= NB_/4)

typedef __attribute__((ext_vector_type(8)))  short short8v;
typedef __attribute__((ext_vector_type(16))) float f32x16;

#if defined(__has_builtin)
#if __has_builtin(__builtin_amdgcn_exp2f)
#define EXP2(x) __builtin_amdgcn_exp2f(x)
#else
#define EXP2(x) exp2f(x)
#endif
#else
#define EXP2(x) exp2f(x)
#endif

__device__ __forceinline__ unsigned short f2bf(float f) {
    unsigned u = __builtin_bit_cast(unsigned, f);
    u = (u + 0x7FFFu + ((u >> 16) & 1u)) >> 16;
    return (unsigned short)u;
}
__device__ __forceinline__ float bf2f(unsigned short h) {
    unsigned u = ((unsigned)h) << 16;
    return __builtin_bit_cast(float, u);
}
__device__ __forceinline__ unsigned cvtpk_bf16(float lo, float hi) {
    unsigned r;
    asm volatile("v_cvt_pk_bf16_f32 %0, %1, %2" : "=v"(r) : "v"(lo), "v"(hi));
    return r;
}
__device__ __forceinline__ void plswap(unsigned &a, unsigned &b) {
    asm volatile("v_permlane32_swap_b32 %0, %1" : "+v"(a), "+v"(b));
}

// DMA: wave-uniform LDS base + lane*16B; per-lane global src.
__device__ __forceinline__ void stage_k(const unsigned short* g,
                                        unsigned short* l_, int w, int ln) {
    #pragma unroll
    for (int i = 0; i < 2; ++i)
        __builtin_amdgcn_global_load_lds(
            (const __attribute__((address_space(1))) void*)(g + i * 2048 + w * 512 + ln * 8),
            (__attribute__((address_space(3))) void*)(l_ + i * 2048 + w * 512), 16, 0, 0);
}
__device__ __forceinline__ void stage_v(const unsigned short* g,
                                        unsigned short* l_, int w, int ln, int t) {
    #pragma unroll
    for (int i = 0; i < 2; ++i)
        __builtin_amdgcn_global_load_lds(
            (const __attribute__((address_space(1))) void*)(g + i * 2048 + w * 512 + ln * 8),
            (__attribute__((address_space(3))) void*)(l_ + i * 2048 + w * 512), 16, 0, 0);
    if (t < 128)
        __builtin_amdgcn_global_load_lds(
            (const __attribute__((address_space(1))) void*)(g + 4096 + w * 512 + ln * 8),
            (__attribute__((address_space(3))) void*)(l_ + 4096 + w * 512), 16, 0, 0);
}

// ---------------------------------------------------------------------------
// Kernel 0: block0 -> W3p [384][88] bf16; blocks 1..144 -> zero Zg (36864 f32)
// ---------------------------------------------------------------------------
__global__ __launch_bounds__(256) void prep_kernel(
    const float* __restrict__ Wq, const float* __restrict__ Wk,
    const float* __restrict__ Wv, unsigned short* __restrict__ W3p,
    float* __restrict__ Zg)
{
    const int t = threadIdx.x;
    if (blockIdx.x == 0) {
        for (int r = t; r < 384; r += 256) {
            const float* src = (r < 128) ? (Wq + r * 66)
                             : (r < 256) ? (Wk + (r - 128) * 66) : (Wv + (r - 256) * 66);
            for (int c = 0; c < 66; ++c) W3p[r * 88 + c] = f2bf(src[c]);
            for (int c = 66; c < 88; ++c) W3p[r * 88 + c] = 0;
        }
    } else {
        Zg[(blockIdx.x - 1) * 256 + t] = 0.0f;
    }
}

// ---------------------------------------------------------------------------
// Kernel 1: QKV projection via MFMA.  Q scaled by S2_ at store time.
// K written directly as swizzled tile images (repackK fused away).
// grid 16b x 18nt(128), 256 thr.
// ---------------------------------------------------------------------------
__global__ __launch_bounds__(256) void qkv_kernel(
    const float* __restrict__ x, const unsigned short* __restrict__ W3p,
    unsigned short* __restrict__ Qb, unsigned short* __restrict__ Ksw,
    unsigned short* __restrict__ Vn)
{
    __shared__ unsigned short Es[128 * 88];
    const int t = threadIdx.x;
    const int b = blockIdx.x / 18, nt = blockIdx.x - b * 18;
    const int n0 = nt * 128;

    {   // x -> Es transposed bf16 (cols 0..63)
        const int d = t & 63, q4 = t >> 6;
        const float* xp = x + ((size_t)b * D_ + d) * N_ + n0 + q4 * 32;
        float xv[32];
        #pragma unroll
        for (int i = 0; i < 8; ++i) *(float4*)(xv + 4 * i) = *(const float4*)(xp + 4 * i);
        #pragma unroll
        for (int i = 0; i < 32; ++i) Es[(q4 * 32 + i) * 88 + d] = f2bf(xv[i]);
    }
    if (t < 128) {  // coords + zero pad
        int n = n0 + t;
        int ix = n / 48, iy = n - ix * 48;
        Es[t * 88 + 64] = f2bf(-1.0f + ((float)ix + 0.5f) * (2.0f / 48.0f));
        Es[t * 88 + 65] = f2bf(-1.0f + ((float)iy + 0.5f) * (2.0f / 48.0f));
        #pragma unroll
        for (int m = 0; m < 11; ++m) *(unsigned*)&Es[t * 88 + 66 + 2 * m] = 0;
    }
    __syncthreads();

    const int l = t & 63, w = t >> 6;
    const int m32 = l & 31, H = l >> 5;
    const int colbase = w * 96;
    #pragma unroll
    for (int nf = 0; nf < 4; ++nf) {
        f32x16 acc[3];
        #pragma unroll
        for (int of = 0; of < 3; ++of)
            #pragma unroll
            for (int i = 0; i < 16; ++i) acc[of][i] = 0.0f;
        #pragma unroll
        for (int kc = 0; kc < 5; ++kc) {
            short8v a = *(const short8v*)&Es[(nf * 32 + m32) * 88 + kc * 16 + H * 8];
            #pragma unroll
            for (int of = 0; of < 3; ++of) {
                short8v bf = *(const short8v*)&W3p[(colbase + of * 32 + m32) * 88 + kc * 16 + H * 8];
                acc[of] = __builtin_amdgcn_mfma_f32_32x32x16_bf16(a, bf, acc[of], 0, 0, 0);
            }
        }
        #pragma unroll
        for (int of = 0; of < 3; ++of) {
            const int col0 = colbase + of * 32;
            const int mi = col0 >> 7, e0 = col0 & 127;
            const int e = e0 + m32;
            if (mi == 0) {          // Q rows, scaled
                #pragma unroll
                for (int r = 0; r < 16; ++r) {
                    int n = n0 + nf * 32 + (r & 3) + 8 * (r >> 2) + 4 * H;
                    Qb[((size_t)b * N_ + n) * DI_ + e] = f2bf(acc[of][r] * S2_);
                }
            } else if (mi == 1) {   // K -> swizzled tile image
                const size_t tbase = ((size_t)b * NKT_ + nt * 4 + nf) * KTSZ_;
                const int cx = e >> 3, ei = e & 7;
                #pragma unroll
                for (int r = 0; r < 16; ++r) {
                    int rr = (r & 3) + 8 * (r >> 2) + 4 * H;
                    Ksw[tbase + rr * 128 + ((cx ^ (rr & 15)) * 8) + ei] = f2bf(acc[of][r]);
                }
            } else {                // V rows
                #pragma unroll
                for (int r = 0; r < 16; ++r) {
                    int n = n0 + nf * 32 + (r & 3) + 8 * (r >> 2) + 4 * H;
                    Vn[((size_t)b * N_ + n) * DI_ + e] = f2bf(acc[of][r]);
                }
            }
        }
    }
}

// ---------------------------------------------------------------------------
// Kernel 2: Zg[b][k] += sum_q exp2(dot(Q',K))  over this block's q-tile.
// grid 1152 (16b x 18qt x 4kh), 256 thr; 18 k-tiles of 32, unrolled x2.
// ---------------------------------------------------------------------------
__global__ __launch_bounds__(256, 4) void zsum_kernel(
    const unsigned short* __restrict__ Qb, const unsigned short* __restrict__ Ksw,
    float* __restrict__ Zg)
{
    __shared__ unsigned short Ks0[KTSZ_], Ks1[KTSZ_];
    __shared__ float Zacc[576];
    const int t = threadIdx.x;
    const int blk = blockIdx.x;
    const int b = 2 * (blk & 7) + ((blk >> 3) & 1);
    const int rest = blk >> 4;           // 0..71
    const int qt = rest % 18, kh = rest / 18;
    const int q0 = qt * 128;
    const int l = t & 63, w = t >> 6;
    const int m32 = l & 31, H = l >> 5;

    for (int i = t; i < 576; i += 256) Zacc[i] = 0.0f;

    short8v qreg[8];
    {
        const unsigned short* qp = Qb + ((size_t)b * N_ + q0 + w * 32 + m32) * DI_ + H * 8;
        #pragma unroll
        for (int ec = 0; ec < 8; ++ec) qreg[ec] = *(const short8v*)(qp + ec * 16);
    }
    int ka[8];
    #pragma unroll
    for (int ec = 0; ec < 8; ++ec)
        ka[ec] = m32 * 128 + (((ec * 2 + H) ^ (m32 & 15)) * 8);

    const unsigned short* kswb = Ksw + ((size_t)b * NKT_ + kh * NKH_) * KTSZ_;
    stage_k(kswb, Ks0, w, l);
    asm volatile("s_waitcnt vmcnt(0)" ::: "memory");
    __syncthreads();

#define ZSUM_STEP(KB, KTC)                                                     \
    {                                                                          \
        f32x16 sa, sb;                                                         \
        _Pragma("unroll") for (int i = 0; i < 16; ++i) { sa[i] = 0.f; sb[i] = 0.f; } \
        __builtin_amdgcn_s_setprio(1);                                         \
        _Pragma("unroll") for (int ec = 0; ec < 8; ++ec) {                     \
            short8v bk = *(const short8v*)&(KB)[ka[ec]];                       \
            if (ec & 1) sb = __builtin_amdgcn_mfma_f32_32x32x16_bf16(qreg[ec], bk, sb, 0, 0, 0); \
            else        sa = __builtin_amdgcn_mfma_f32_32x32x16_bf16(qreg[ec], bk, sa, 0, 0, 0); \
        }                                                                      \
        __builtin_amdgcn_s_setprio(0);                                         \
        float zl = 0.0f;                                                       \
        _Pragma("unroll") for (int r = 0; r < 16; ++r) zl += EXP2(sa[r] + sb[r]); \
        atomicAdd(&Zacc[(KTC) * 32 + m32], zl);                                \
        asm volatile("s_waitcnt vmcnt(0)" ::: "memory");                       \
        __syncthreads();                                                       \
    }

    for (int kt = 0; kt < NKH_; kt += 2) {
        stage_k(kswb + (size_t)(kt + 1) * KTSZ_, Ks1, w, l);
        ZSUM_STEP(Ks0, kt);
        if (kt + 2 < NKH_) stage_k(kswb + (size_t)(kt + 2) * KTSZ_, Ks0, w, l);
        ZSUM_STEP(Ks1, kt + 1);
    }
    for (int i = t; i < 576; i += 256)
        atomicAdd(&Zg[(size_t)b * N_ + kh * 576 + i], Zacc[i]);
}

// ---------------------------------------------------------------------------
// Kernel 3: Vn + Zg -> Vsw tiles [128 d][pitch 40] (/Z folded)
// grid 16 x 72, 256 thr.
// ---------------------------------------------------------------------------
__global__ __launch_bounds__(256) void repackV_kernel(
    const unsigned short* __restrict__ Vn, const float* __restrict__ Zg,
    unsigned short* __restrict__ Vsw)
{
    __shared__ unsigned short Vstg[32 * 132];
    __shared__ float zinv[32];
    const int blk = blockIdx.x;
    const int b = blk / NKT_, kt = blk - b * NKT_;
    const int t = threadIdx.x;
    const int k0 = kt * 32;
    {
        const int k = t >> 3, c = (t & 7) * 16;
        const unsigned short* src = Vn + ((size_t)b * N_ + k0 + k) * DI_ + c;
        *(int4*)&Vstg[k * 132 + c]     = *(const int4*)(src);
        *(int4*)&Vstg[k * 132 + c + 8] = *(const int4*)(src + 8);
    }
    if (t < 32) zinv[t] = 1.0f / Zg[(size_t)b * N_ + k0 + t];
    __syncthreads();
    unsigned short* dstt = Vsw + ((size_t)b * NKT_ + kt) * VTSZ_;
    const int d = t & 127, part = t >> 7;
    #pragma unroll
    for (int g = 0; g < 4; ++g) {
        unsigned short sv[4];
        #pragma unroll
        for (int j = 0; j < 4; ++j) {
            int k = part * 16 + g * 4 + j;
            sv[j] = f2bf(bf2f(Vstg[k * 132 + d]) * zinv[k]);
        }
        *(int2*)(dstt + d * 40 + part * 16 + g * 4) = *(const int2*)sv;
    }
}

// ---------------------------------------------------------------------------
// Kernel 4: partial Out^T = Vz^T . P over one kh quarter.
// grid 1152 (16b x 18qt x 4kh), 256 thr; kh0 -> out, kh1..3 -> Op[kh-1].
// ---------------------------------------------------------------------------
__global__ __launch_bounds__(256, 3) void attn_kernel(
    const unsigned short* __restrict__ Qb, const unsigned short* __restrict__ Ksw,
    const unsigned short* __restrict__ Vsw,
    float* __restrict__ O0, float* __restrict__ Op)
{
    __shared__ unsigned short Ks0[KTSZ_], Ks1[KTSZ_];
    __shared__ unsigned short Vs0[VTSZ_], Vs1[VTSZ_];
    const int t = threadIdx.x;
    const int blk = blockIdx.x;
    const int b = 2 * (blk & 7) + ((blk >> 3) & 1);
    const int rest = blk >> 4;
    const int qt = rest % 18, kh = rest / 18;
    const int q0 = qt * 128;
    const int l = t & 63, w = t >> 6;
    const int m32 = l & 31, H = l >> 5;

    short8v qreg[8];
    {
        const unsigned short* qp = Qb + ((size_t)b * N_ + q0 + w * 32 + m32) * DI_ + H * 8;
        #pragma unroll
        for (int ec = 0; ec < 8; ++ec) qreg[ec] = *(const short8v*)(qp + ec * 16);
    }
    f32x16 oacc[4];
    #pragma unroll
    for (int df = 0; df < 4; ++df)
        #pragma unroll
        for (int i = 0; i < 16; ++i) oacc[df][i] = 0.0f;

    int ka[8];
    #pragma unroll
    for (int ec = 0; ec < 8; ++ec)
        ka[ec] = m32 * 128 + (((ec * 2 + H) ^ (m32 & 15)) * 8);
    const int vb0 = m32 * 40 + H * 8;

    const unsigned short* kswb = Ksw + ((size_t)b * NKT_ + kh * NKH_) * KTSZ_;
    const unsigned short* vswb = Vsw + ((size_t)b * NKT_ + kh * NKH_) * VTSZ_;
    stage_k(kswb, Ks0, w, l);
    stage_v(vswb, Vs0, w, l, t);
    asm volatile("s_waitcnt vmcnt(0)" ::: "memory");
    __syncthreads();

#define ATTN_STEP(KB, VB)                                                      \
    {                                                                          \
        f32x16 sa, sb;                                                         \
        _Pragma("unroll") for (int i = 0; i < 16; ++i) { sa[i] = 0.f; sb[i] = 0.f; } \
        __builtin_amdgcn_s_setprio(1);                                         \
        _Pragma("unroll") for (int ec = 0; ec < 8; ++ec) {                     \
            short8v ak = *(const short8v*)&(KB)[ka[ec]];                       \
            if (ec & 1) sb = __builtin_amdgcn_mfma_f32_32x32x16_bf16(ak, qreg[ec], sb, 0, 0, 0); \
            else        sa = __builtin_amdgcn_mfma_f32_32x32x16_bf16(ak, qreg[ec], sa, 0, 0, 0); \
        }                                                                      \
        __builtin_amdgcn_s_setprio(0);                                         \
        float p[16];                                                           \
        _Pragma("unroll") for (int r = 0; r < 16; ++r) p[r] = EXP2(sa[r] + sb[r]); \
        unsigned c0[4], c1[4];                                                 \
        _Pragma("unroll") for (int m = 0; m < 4; ++m) {                        \
            c0[m] = cvtpk_bf16(p[4 * m],     p[4 * m + 1]);                    \
            c1[m] = cvtpk_bf16(p[4 * m + 2], p[4 * m + 3]);                    \
        }                                                                      \
        short8v pB[2];                                                         \
        _Pragma("unroll") for (int kq = 0; kq < 2; ++kq) {                     \
            unsigned d0 = c0[2 * kq], d2 = c0[2 * kq + 1]; plswap(d0, d2);     \
            unsigned d1 = c1[2 * kq], d3 = c1[2 * kq + 1]; plswap(d1, d3);     \
            int4 t4; t4.x = (int)d0; t4.y = (int)d1; t4.z = (int)d2; t4.w = (int)d3; \
            pB[kq] = __builtin_bit_cast(short8v, t4);                          \
        }                                                                      \
        __builtin_amdgcn_s_setprio(1);                                         \
        _Pragma("unroll") for (int df = 0; df < 4; ++df) {                     \
            _Pragma("unroll") for (int kq = 0; kq < 2; ++kq) {                 \
                short8v av = *(const short8v*)&(VB)[vb0 + df * 1280 + kq * 16]; \
                oacc[df] = __builtin_amdgcn_mfma_f32_32x32x16_bf16(av, pB[kq], oacc[df], 0, 0, 0); \
            }                                                                  \
        }                                                                      \
        __builtin_amdgcn_s_setprio(0);                                         \
        asm volatile("s_waitcnt vmcnt(0)" ::: "memory");                       \
        __syncthreads();                                                       \
    }

    for (int kt = 0; kt < NKH_; kt += 2) {
        stage_k(kswb + (size_t)(kt + 1) * KTSZ_, Ks1, w, l);
        stage_v(vswb + (size_t)(kt + 1) * VTSZ_, Vs1, w, l, t);
        ATTN_STEP(Ks0, Vs0);
        if (kt + 2 < NKH_) {
            stage_k(kswb + (size_t)(kt + 2) * KTSZ_, Ks0, w, l);
            stage_v(vswb + (size_t)(kt + 2) * VTSZ_, Vs0, w, l, t);
        }
        ATTN_STEP(Ks1, Vs1);
    }

    float* outp = (kh == 0 ? O0 : (Op + (size_t)(kh - 1) * NB_))
                + ((size_t)b * N_ + q0 + w * 32 + m32) * DI_;
    #pragma unroll
    for (int df = 0; df < 4; ++df)
        #pragma unroll
        for (int r = 0; r < 16; ++r) {
            int d = df * 32 + (r & 3) + 8 * (r >> 2) + 4 * H;
            outp[d] = oacc[df][r];
        }
}

// ---------------------------------------------------------------------------
// Kernel 5: out += Op0 + Op1 + Op2.  One float4/thread, grid 4608 x 256
// (4608*256 = 1179648 = OF4_ float4s = NB_ floats).  Partial stride = OF4_.
// ---------------------------------------------------------------------------
__global__ __launch_bounds__(256) void reduce_kernel(
    float* __restrict__ out, const float* __restrict__ part)
{
    const size_t idx = (size_t)blockIdx.x * 256 + threadIdx.x;
    float4 p0 = ((const float4*)part)[idx];
    float4 p1 = ((const float4*)part)[idx + (size_t)OF4_];
    float4 p2 = ((const float4*)part)[idx + 2 * (size_t)OF4_];
    float4 o  = ((float4*)out)[idx];
    o.x += p0.x + p1.x + p2.x;
    o.y += p0.y + p1.y + p2.y;
    o.z += p0.z + p1.z + p2.z;
    o.w += p0.w + p1.w + p2.w;
    ((float4*)out)[idx] = o;
}

// ---------------------------------------------------------------------------
extern "C" void kernel_launch(void* const* d_in, const int* in_sizes, int n_in,
                              void* d_out, int out_size, void* d_ws, size_t ws_size,
                              hipStream_t stream)
{
    const float* x  = (const float*)d_in[0];
    const float* Wq = (const float*)d_in[1];
    const float* Wk = (const float*)d_in[2];
    const float* Wv = (const float*)d_in[3];

    // Layout (87.5 MB total). Vn is aliased into the head of the Op region:
    // Vn is dead after repackV completes; Op is first written by attn, which
    // launches after repackV (stream-ordered) — no lifetime overlap.
    unsigned short* Qb  = (unsigned short*)d_ws;            // [B][N][128] (pre-scaled)
    unsigned short* Ksw = Qb  + NB_;                        // [B][72] swizzled K tiles
    unsigned short* Vsw = Ksw + NB_;                        // [B][72] V tiles pitch 40
    unsigned short* W3p = Vsw + (size_t)B_ * NKT_ * VTSZ_;  // [384][88]
    float*          Zg  = (float*)(W3p + 384 * 88);         // [B][N]
    float*          Op  = Zg + (size_t)B_ * N_;             // 3 x [B][N][128] partials
    unsigned short* Vn  = (unsigned short*)Op;              // [B][N][128] (aliased)
    float* out = (float*)d_out;

    prep_kernel   <<<145,  256, 0, stream>>>(Wq, Wk, Wv, W3p, Zg);
    qkv_kernel    <<<288,  256, 0, stream>>>(x, W3p, Qb, Ksw, Vn);
    zsum_kernel   <<<1152, 256, 0, stream>>>(Qb, Ksw, Zg);
    repackV_kernel<<<1152, 256, 0, stream>>>(Vn, Zg, Vsw);
    attn_kernel   <<<1152, 256, 0, stream>>>(Qb, Ksw, Vsw, out, Op);
    reduce_kernel <<<4608, 256, 0, stream>>>(out, Op);
}

// Round 11
// 146.465 us; speedup vs baseline: 1.6078x; 1.0553x over previous
//
#include <hip/hip_runtime.h>
#include <cstdint>

#define B_    16
#define D_    64
#define N_    2304
#define DI_   128
#define S2_   0.12751875732488788f    // (1/sqrt(128)) * log2(e)  -- folded into Q
#define NB_   ((size_t)B_ * N_ * DI_)
#define KTSZ_ 4096                    // K tile: 32k x 128e shorts (swizzled image)
#define VTSZ_ 5120                    // V tile: 128d x 40k shorts (16B-aligned pitch)
#define NKT_  72                      // 32-row k tiles per batch
#define NKH_  18                      // k tiles per kh quarter
#define OF4_  1179648                 // float4s per partial (= NB_/4)

typedef __attribute__((ext_vector_type(8)))  short short8v;
typedef __attribute__((ext_vector_type(16))) float f32x16;

#if defined(__has_builtin)
#if __has_builtin(__builtin_amdgcn_exp2f)
#define EXP2(x) __builtin_amdgcn_exp2f(x)
#else
#define EXP2(x) exp2f(x)
#endif
#else
#define EXP2(x) exp2f(x)
#endif

__device__ __forceinline__ unsigned short f2bf(float f) {
    unsigned u = __builtin_bit_cast(unsigned, f);
    u = (u + 0x7FFFu + ((u >> 16) & 1u)) >> 16;
    return (unsigned short)u;
}
__device__ __forceinline__ float bf2f(unsigned short h) {
    unsigned u = ((unsigned)h) << 16;
    return __builtin_bit_cast(float, u);
}
__device__ __forceinline__ unsigned cvtpk_bf16(float lo, float hi) {
    unsigned r;
    asm volatile("v_cvt_pk_bf16_f32 %0, %1, %2" : "=v"(r) : "v"(lo), "v"(hi));
    return r;
}
__device__ __forceinline__ void plswap(unsigned &a, unsigned &b) {
    asm volatile("v_permlane32_swap_b32 %0, %1" : "+v"(a), "+v"(b));
}

// DMA: wave-uniform LDS base + lane*16B; per-lane global src.
__device__ __forceinline__ void stage_k(const unsigned short* g,
                                        unsigned short* l_, int w, int ln) {
    #pragma unroll
    for (int i = 0; i < 2; ++i)
        __builtin_amdgcn_global_load_lds(
            (const __attribute__((address_space(1))) void*)(g + i * 2048 + w * 512 + ln * 8),
            (__attribute__((address_space(3))) void*)(l_ + i * 2048 + w * 512), 16, 0, 0);
}
__device__ __forceinline__ void stage_v(const unsigned short* g,
                                        unsigned short* l_, int w, int ln, int t) {
    #pragma unroll
    for (int i = 0; i < 2; ++i)
        __builtin_amdgcn_global_load_lds(
            (const __attribute__((address_space(1))) void*)(g + i * 2048 + w * 512 + ln * 8),
            (__attribute__((address_space(3))) void*)(l_ + i * 2048 + w * 512), 16, 0, 0);
    if (t < 128)
        __builtin_amdgcn_global_load_lds(
            (const __attribute__((address_space(1))) void*)(g + 4096 + w * 512 + ln * 8),
            (__attribute__((address_space(3))) void*)(l_ + 4096 + w * 512), 16, 0, 0);
}

// ---------------------------------------------------------------------------
// Kernel 0: block0 -> W3p [384][88] bf16; blocks 1..144 -> zero Zg (36864 f32)
// ---------------------------------------------------------------------------
__global__ __launch_bounds__(256) void prep_kernel(
    const float* __restrict__ Wq, const float* __restrict__ Wk,
    const float* __restrict__ Wv, unsigned short* __restrict__ W3p,
    float* __restrict__ Zg)
{
    const int t = threadIdx.x;
    if (blockIdx.x == 0) {
        for (int r = t; r < 384; r += 256) {
            const float* src = (r < 128) ? (Wq + r * 66)
                             : (r < 256) ? (Wk + (r - 128) * 66) : (Wv + (r - 256) * 66);
            for (int c = 0; c < 66; ++c) W3p[r * 88 + c] = f2bf(src[c]);
            for (int c = 66; c < 88; ++c) W3p[r * 88 + c] = 0;
        }
    } else {
        Zg[(blockIdx.x - 1) * 256 + t] = 0.0f;
    }
}

// ---------------------------------------------------------------------------
// Kernel 1: QKV projection via MFMA.  Q scaled by S2_ at store time.
// K written directly as swizzled tile images.  grid 16b x 18nt(128), 256 thr.
// (verified r7)
// ---------------------------------------------------------------------------
__global__ __launch_bounds__(256) void qkv_kernel(
    const float* __restrict__ x, const unsigned short* __restrict__ W3p,
    unsigned short* __restrict__ Qb, unsigned short* __restrict__ Ksw,
    unsigned short* __restrict__ Vn)
{
    __shared__ unsigned short Es[128 * 88];
    const int t = threadIdx.x;
    const int b = blockIdx.x / 18, nt = blockIdx.x - b * 18;
    const int n0 = nt * 128;

    {   // x -> Es transposed bf16 (cols 0..63)
        const int d = t & 63, q4 = t >> 6;
        const float* xp = x + ((size_t)b * D_ + d) * N_ + n0 + q4 * 32;
        float xv[32];
        #pragma unroll
        for (int i = 0; i < 8; ++i) *(float4*)(xv + 4 * i) = *(const float4*)(xp + 4 * i);
        #pragma unroll
        for (int i = 0; i < 32; ++i) Es[(q4 * 32 + i) * 88 + d] = f2bf(xv[i]);
    }
    if (t < 128) {  // coords + zero pad
        int n = n0 + t;
        int ix = n / 48, iy = n - ix * 48;
        Es[t * 88 + 64] = f2bf(-1.0f + ((float)ix + 0.5f) * (2.0f / 48.0f));
        Es[t * 88 + 65] = f2bf(-1.0f + ((float)iy + 0.5f) * (2.0f / 48.0f));
        #pragma unroll
        for (int m = 0; m < 11; ++m) *(unsigned*)&Es[t * 88 + 66 + 2 * m] = 0;
    }
    __syncthreads();

    const int l = t & 63, w = t >> 6;
    const int m32 = l & 31, H = l >> 5;
    const int colbase = w * 96;
    #pragma unroll
    for (int nf = 0; nf < 4; ++nf) {
        f32x16 acc[3];
        #pragma unroll
        for (int of = 0; of < 3; ++of)
            #pragma unroll
            for (int i = 0; i < 16; ++i) acc[of][i] = 0.0f;
        #pragma unroll
        for (int kc = 0; kc < 5; ++kc) {
            short8v a = *(const short8v*)&Es[(nf * 32 + m32) * 88 + kc * 16 + H * 8];
            #pragma unroll
            for (int of = 0; of < 3; ++of) {
                short8v bf = *(const short8v*)&W3p[(colbase + of * 32 + m32) * 88 + kc * 16 + H * 8];
                acc[of] = __builtin_amdgcn_mfma_f32_32x32x16_bf16(a, bf, acc[of], 0, 0, 0);
            }
        }
        #pragma unroll
        for (int of = 0; of < 3; ++of) {
            const int col0 = colbase + of * 32;
            const int mi = col0 >> 7, e0 = col0 & 127;
            const int e = e0 + m32;
            if (mi == 0) {          // Q rows, scaled
                #pragma unroll
                for (int r = 0; r < 16; ++r) {
                    int n = n0 + nf * 32 + (r & 3) + 8 * (r >> 2) + 4 * H;
                    Qb[((size_t)b * N_ + n) * DI_ + e] = f2bf(acc[of][r] * S2_);
                }
            } else if (mi == 1) {   // K -> swizzled tile image
                const size_t tbase = ((size_t)b * NKT_ + nt * 4 + nf) * KTSZ_;
                const int cx = e >> 3, ei = e & 7;
                #pragma unroll
                for (int r = 0; r < 16; ++r) {
                    int rr = (r & 3) + 8 * (r >> 2) + 4 * H;
                    Ksw[tbase + rr * 128 + ((cx ^ (rr & 15)) * 8) + ei] = f2bf(acc[of][r]);
                }
            } else {                // V rows
                #pragma unroll
                for (int r = 0; r < 16; ++r) {
                    int n = n0 + nf * 32 + (r & 3) + 8 * (r >> 2) + 4 * H;
                    Vn[((size_t)b * N_ + n) * DI_ + e] = f2bf(acc[of][r]);
                }
            }
        }
    }
}

// ---------------------------------------------------------------------------
// Kernel 2: Zg[b][k] += sum_q exp2(dot(Q',K)).  grid 576 (16b x 9qt x 4kh),
// 256 thr; wave owns 64 q (2 frags -> 2 MFMA per LDS read).  r7 sync:
// stage at top, vmcnt(0)+__syncthreads() at bottom of each step.
// ---------------------------------------------------------------------------
__global__ __launch_bounds__(256, 3) void zsum_kernel(
    const unsigned short* __restrict__ Qb, const unsigned short* __restrict__ Ksw,
    float* __restrict__ Zg)
{
    __shared__ unsigned short Ks0[KTSZ_], Ks1[KTSZ_];
    __shared__ float Zacc[576];
    const int t = threadIdx.x;
    const int blk = blockIdx.x;
    const int b = 2 * (blk & 7) + ((blk >> 3) & 1);
    const int rest = blk >> 4;           // 0..35
    const int qt = rest % 9, kh = rest / 9;
    const int q0 = qt * 256;
    const int l = t & 63, w = t >> 6;
    const int m32 = l & 31, H = l >> 5;

    for (int i = t; i < 576; i += 256) Zacc[i] = 0.0f;

    short8v qreg[2][8];   // A-frags [32q x 16e], wave owns 64 q rows
    {
        const unsigned short* qp = Qb + ((size_t)b * N_ + q0 + w * 64 + m32) * DI_ + H * 8;
        #pragma unroll
        for (int qf = 0; qf < 2; ++qf)
            #pragma unroll
            for (int ec = 0; ec < 8; ++ec)
                qreg[qf][ec] = *(const short8v*)(qp + (size_t)qf * 32 * DI_ + ec * 16);
    }
    int ka[8];
    #pragma unroll
    for (int ec = 0; ec < 8; ++ec)
        ka[ec] = m32 * 128 + (((ec * 2 + H) ^ (m32 & 15)) * 8);

    const unsigned short* kswb = Ksw + ((size_t)b * NKT_ + kh * NKH_) * KTSZ_;
    stage_k(kswb, Ks0, w, l);
    asm volatile("s_waitcnt vmcnt(0)" ::: "memory");
    __syncthreads();

#define ZSTEP(KB, KTC)                                                         \
    {                                                                          \
        f32x16 s0, s1;                                                         \
        _Pragma("unroll") for (int i = 0; i < 16; ++i) { s0[i] = 0.f; s1[i] = 0.f; } \
        __builtin_amdgcn_s_setprio(1);                                         \
        _Pragma("unroll") for (int ec = 0; ec < 8; ++ec) {                     \
            short8v bk = *(const short8v*)&(KB)[ka[ec]];                       \
            s0 = __builtin_amdgcn_mfma_f32_32x32x16_bf16(qreg[0][ec], bk, s0, 0, 0, 0); \
            s1 = __builtin_amdgcn_mfma_f32_32x32x16_bf16(qreg[1][ec], bk, s1, 0, 0, 0); \
        }                                                                      \
        __builtin_amdgcn_s_setprio(0);                                         \
        float zl = 0.0f;                                                       \
        _Pragma("unroll") for (int r = 0; r < 16; ++r)                         \
            zl += EXP2(s0[r]) + EXP2(s1[r]);                                   \
        atomicAdd(&Zacc[(KTC) * 32 + m32], zl);                                \
        asm volatile("s_waitcnt vmcnt(0)" ::: "memory");                       \
        __syncthreads();                                                       \
    }

    for (int g = 0; g < 9; ++g) {
        const int kt = 2 * g;
        stage_k(kswb + (size_t)(kt + 1) * KTSZ_, Ks1, w, l);
        ZSTEP(Ks0, kt);
        if (kt + 2 < NKH_) stage_k(kswb + (size_t)(kt + 2) * KTSZ_, Ks0, w, l);
        ZSTEP(Ks1, kt + 1);
    }
#undef ZSTEP

    for (int i = t; i < 576; i += 256)
        atomicAdd(&Zg[(size_t)b * N_ + kh * 576 + i], Zacc[i]);
}

// ---------------------------------------------------------------------------
// Kernel 3: Vn + Zg -> Vsw tiles [128 d][pitch 40] (/Z folded).  grid 16 x 72.
// (verified r7)
// ---------------------------------------------------------------------------
__global__ __launch_bounds__(256) void repackV_kernel(
    const unsigned short* __restrict__ Vn, const float* __restrict__ Zg,
    unsigned short* __restrict__ Vsw)
{
    __shared__ unsigned short Vstg[32 * 132];
    __shared__ float zinv[32];
    const int blk = blockIdx.x;
    const int b = blk / NKT_, kt = blk - b * NKT_;
    const int t = threadIdx.x;
    const int k0 = kt * 32;
    {
        const int k = t >> 3, c = (t & 7) * 16;
        const unsigned short* src = Vn + ((size_t)b * N_ + k0 + k) * DI_ + c;
        *(int4*)&Vstg[k * 132 + c]     = *(const int4*)(src);
        *(int4*)&Vstg[k * 132 + c + 8] = *(const int4*)(src + 8);
    }
    if (t < 32) zinv[t] = 1.0f / Zg[(size_t)b * N_ + k0 + t];
    __syncthreads();
    unsigned short* dstt = Vsw + ((size_t)b * NKT_ + kt) * VTSZ_;
    const int d = t & 127, part = t >> 7;
    #pragma unroll
    for (int g = 0; g < 4; ++g) {
        unsigned short sv[4];
        #pragma unroll
        for (int j = 0; j < 4; ++j) {
            int k = part * 16 + g * 4 + j;
            sv[j] = f2bf(bf2f(Vstg[k * 132 + d]) * zinv[k]);
        }
        *(int2*)(dstt + d * 40 + part * 16 + g * 4) = *(const int2*)sv;
    }
}

// ---------------------------------------------------------------------------
// Kernel 4: partial Out^T = Vz^T . P over one kh quarter.
// grid 1152 (16b x 18qt x 4kh), 256 thr; kh0 -> out, kh1..3 -> Op[kh-1].
// r7 sync (stage top, vmcnt(0)+__syncthreads() bottom); merged sacc chain +
// fused exp2->cvt_pk for register trim (target <=170 unified regs, 3 blk/CU).
// ---------------------------------------------------------------------------
__global__ __launch_bounds__(256, 3) void attn_kernel(
    const unsigned short* __restrict__ Qb, const unsigned short* __restrict__ Ksw,
    const unsigned short* __restrict__ Vsw,
    float* __restrict__ O0, float* __restrict__ Op)
{
    __shared__ unsigned short Ks0[KTSZ_], Ks1[KTSZ_];
    __shared__ unsigned short Vs0[VTSZ_], Vs1[VTSZ_];
    const int t = threadIdx.x;
    const int blk = blockIdx.x;
    const int b = 2 * (blk & 7) + ((blk >> 3) & 1);
    const int rest = blk >> 4;
    const int qt = rest % 18, kh = rest / 18;
    const int q0 = qt * 128;
    const int l = t & 63, w = t >> 6;
    const int m32 = l & 31, H = l >> 5;

    short8v qreg[8];
    {
        const unsigned short* qp = Qb + ((size_t)b * N_ + q0 + w * 32 + m32) * DI_ + H * 8;
        #pragma unroll
        for (int ec = 0; ec < 8; ++ec) qreg[ec] = *(const short8v*)(qp + ec * 16);
    }
    f32x16 oacc[4];
    #pragma unroll
    for (int df = 0; df < 4; ++df)
        #pragma unroll
        for (int i = 0; i < 16; ++i) oacc[df][i] = 0.0f;

    int ka[8];
    #pragma unroll
    for (int ec = 0; ec < 8; ++ec)
        ka[ec] = m32 * 128 + (((ec * 2 + H) ^ (m32 & 15)) * 8);
    const int vb0 = m32 * 40 + H * 8;

    const unsigned short* kswb = Ksw + ((size_t)b * NKT_ + kh * NKH_) * KTSZ_;
    const unsigned short* vswb = Vsw + ((size_t)b * NKT_ + kh * NKH_) * VTSZ_;
    stage_k(kswb, Ks0, w, l);
    stage_v(vswb, Vs0, w, l, t);
    asm volatile("s_waitcnt vmcnt(0)" ::: "memory");
    __syncthreads();

#define PSTEP(KB, VB)                                                          \
    {                                                                          \
        f32x16 sacc;                                                           \
        _Pragma("unroll") for (int i = 0; i < 16; ++i) sacc[i] = 0.f;          \
        __builtin_amdgcn_s_setprio(1);                                         \
        _Pragma("unroll") for (int ec = 0; ec < 8; ++ec) {                     \
            short8v ak = *(const short8v*)&(KB)[ka[ec]];                       \
            sacc = __builtin_amdgcn_mfma_f32_32x32x16_bf16(ak, qreg[ec], sacc, 0, 0, 0); \
        }                                                                      \
        __builtin_amdgcn_s_setprio(0);                                         \
        unsigned c0[4], c1[4];                                                 \
        _Pragma("unroll") for (int m = 0; m < 4; ++m) {                        \
            float e0 = EXP2(sacc[4 * m]),     e1 = EXP2(sacc[4 * m + 1]);      \
            float e2 = EXP2(sacc[4 * m + 2]), e3 = EXP2(sacc[4 * m + 3]);      \
            c0[m] = cvtpk_bf16(e0, e1);                                        \
            c1[m] = cvtpk_bf16(e2, e3);                                        \
        }                                                                      \
        short8v pB[2];                                                         \
        _Pragma("unroll") for (int kq = 0; kq < 2; ++kq) {                     \
            unsigned d0 = c0[2 * kq], d2 = c0[2 * kq + 1]; plswap(d0, d2);     \
            unsigned d1 = c1[2 * kq], d3 = c1[2 * kq + 1]; plswap(d1, d3);     \
            int4 t4; t4.x = (int)d0; t4.y = (int)d1; t4.z = (int)d2; t4.w = (int)d3; \
            pB[kq] = __builtin_bit_cast(short8v, t4);                          \
        }                                                                      \
        __builtin_amdgcn_s_setprio(1);                                         \
        _Pragma("unroll") for (int df = 0; df < 4; ++df) {                     \
            _Pragma("unroll") for (int kq = 0; kq < 2; ++kq) {                 \
                short8v av = *(const short8v*)&(VB)[vb0 + df * 1280 + kq * 16]; \
                oacc[df] = __builtin_amdgcn_mfma_f32_32x32x16_bf16(av, pB[kq], oacc[df], 0, 0, 0); \
            }                                                                  \
        }                                                                      \
        __builtin_amdgcn_s_setprio(0);                                         \
        asm volatile("s_waitcnt vmcnt(0)" ::: "memory");                       \
        __syncthreads();                                                       \
    }

    for (int kt = 0; kt < NKH_; kt += 2) {
        stage_k(kswb + (size_t)(kt + 1) * KTSZ_, Ks1, w, l);
        stage_v(vswb + (size_t)(kt + 1) * VTSZ_, Vs1, w, l, t);
        PSTEP(Ks0, Vs0);
        if (kt + 2 < NKH_) {
            stage_k(kswb + (size_t)(kt + 2) * KTSZ_, Ks0, w, l);
            stage_v(vswb + (size_t)(kt + 2) * VTSZ_, Vs0, w, l, t);
        }
        PSTEP(Ks1, Vs1);
    }
#undef PSTEP

    float* outp = (kh == 0 ? O0 : (Op + (size_t)(kh - 1) * NB_))
                + ((size_t)b * N_ + q0 + w * 32 + m32) * DI_;
    #pragma unroll
    for (int df = 0; df < 4; ++df)
        #pragma unroll
        for (int r = 0; r < 16; ++r) {
            int d = df * 32 + (r & 3) + 8 * (r >> 2) + 4 * H;
            outp[d] = oacc[df][r];
        }
}

// ---------------------------------------------------------------------------
// Kernel 5: out += Op0 + Op1 + Op2.  One float4/thread, grid 4608 x 256.
// ---------------------------------------------------------------------------
__global__ __launch_bounds__(256) void reduce_kernel(
    float* __restrict__ out, const float* __restrict__ part)
{
    const size_t idx = (size_t)blockIdx.x * 256 + threadIdx.x;
    float4 p0 = ((const float4*)part)[idx];
    float4 p1 = ((const float4*)part)[idx + (size_t)OF4_];
    float4 p2 = ((const float4*)part)[idx + 2 * (size_t)OF4_];
    float4 o  = ((float4*)out)[idx];
    o.x += p0.x + p1.x + p2.x;
    o.y += p0.y + p1.y + p2.y;
    o.z += p0.z + p1.z + p2.z;
    o.w += p0.w + p1.w + p2.w;
    ((float4*)out)[idx] = o;
}

// ---------------------------------------------------------------------------
extern "C" void kernel_launch(void* const* d_in, const int* in_sizes, int n_in,
                              void* d_out, int out_size, void* d_ws, size_t ws_size,
                              hipStream_t stream)
{
    const float* x  = (const float*)d_in[0];
    const float* Wq = (const float*)d_in[1];
    const float* Wk = (const float*)d_in[2];
    const float* Wv = (const float*)d_in[3];

    // Vn aliases the head of Op: Vn dead after repackV; Op first written by
    // attn (launched later, stream-ordered).
    unsigned short* Qb  = (unsigned short*)d_ws;            // [B][N][128] (pre-scaled)
    unsigned short* Ksw = Qb  + NB_;                        // [B][72] swizzled K tiles
    unsigned short* Vsw = Ksw + NB_;                        // [B][72] V tiles pitch 40
    unsigned short* W3p = Vsw + (size_t)B_ * NKT_ * VTSZ_;  // [384][88]
    float*          Zg  = (float*)(W3p + 384 * 88);         // [B][N]
    float*          Op  = Zg + (size_t)B_ * N_;             // 3 x [B][N][128] partials
    unsigned short* Vn  = (unsigned short*)Op;              // [B][N][128] (aliased)
    float* out = (float*)d_out;

    prep_kernel   <<<145,  256, 0, stream>>>(Wq, Wk, Wv, W3p, Zg);
    qkv_kernel    <<<288,  256, 0, stream>>>(x, W3p, Qb, Ksw, Vn);
    zsum_kernel   <<<576,  256, 0, stream>>>(Qb, Ksw, Zg);
    repackV_kernel<<<1152, 256, 0, stream>>>(Vn, Zg, Vsw);
    attn_kernel   <<<1152, 256, 0, stream>>>(Qb, Ksw, Vsw, out, Op);
    reduce_kernel <<<4608, 256, 0, stream>>>(out, Op);
}